// Round 4
// baseline (1480.367 us; speedup 1.0000x reference)
//
#include <hip/hip_runtime.h>

#define INF_F __builtin_inff()

// ===========================================================================
// Spatial-bin exact kNN.
// Grid 6^4 over [0,1]^4. Counting-sort points by cell; one THREAD per target
// scans expanding Chebyshev shells keeping a register top-16 (tracked worst).
// Key = (dist_bits<<32)|j : u64 ascending == (dist, index) lexicographic ==
// reference top_k order (dist >= 0, indices unique -> keys unique).
// Exactness: before shell m, any unseen point has true d^2 > ((m-1)*w)^2
// (cells differing by >= m along an axis force coord diff > (m-1)*w... strict
// bound with w = 1/6); computed d has rel err <= ~6 ulp, so breaking when
// tau < LB^2*(1-1e-5) can never discard a true top-16 member.
// Distance arithmetic matches the reference bit-for-bit: contract off,
// separately rounded squares, sequential sum.
// ===========================================================================
#define KNN_G 6
#define KNN_NC (KNN_G*KNN_G*KNN_G*KNN_G)   // 1296

__global__ __launch_bounds__(256) void bin_count_kernel(
    const float* __restrict__ loc, int* __restrict__ cellcount,
    int* __restrict__ cellid, int n)
{
  const int i = blockIdx.x * 256 + threadIdx.x;
  if (i >= n) return;
  const float4 l = *(const float4*)(loc + (size_t)i*4);
  const int cx = min(KNN_G-1, (int)(l.x * (float)KNN_G));
  const int cy = min(KNN_G-1, (int)(l.y * (float)KNN_G));
  const int cz = min(KNN_G-1, (int)(l.z * (float)KNN_G));
  const int cw = min(KNN_G-1, (int)(l.w * (float)KNN_G));
  const int c = ((cx*KNN_G + cy)*KNN_G + cz)*KNN_G + cw;
  cellid[i] = c;
  atomicAdd(&cellcount[c], 1);
}

__global__ __launch_bounds__(256) void bin_scatter_kernel(
    const float* __restrict__ loc, const int* __restrict__ cellid,
    const int* __restrict__ cellstart, int* __restrict__ cellfill,
    float* __restrict__ locs4s, int* __restrict__ oidx, int n)
{
  const int i = blockIdx.x * 256 + threadIdx.x;
  if (i >= n) return;
  const int c = cellid[i];
  const int pos = cellstart[c] + atomicAdd(&cellfill[c], 1);
  *(float4*)(locs4s + (size_t)pos*4) = *(const float4*)(loc + (size_t)i*4);
  oidx[pos] = i;
}

__global__ __launch_bounds__(256) void knn_binned_kernel(
    const float* __restrict__ locs4s, const int* __restrict__ oidx,
    const int* __restrict__ cellstart, int* __restrict__ knn, int n)
{
#pragma clang fp contract(off)
  const int t = blockIdx.x * 256 + threadIdx.x;
  if (t >= n) return;
  const int i = oidx[t];
  const float4 L = *(const float4*)(locs4s + (size_t)t*4);
  const float tx = L.x, ty = L.y, tz = L.z, tw = L.w;
  const int cx = min(KNN_G-1, (int)(tx * (float)KNN_G));
  const int cy = min(KNN_G-1, (int)(ty * (float)KNN_G));
  const int cz = min(KNN_G-1, (int)(tz * (float)KNN_G));
  const int cw = min(KNN_G-1, (int)(tw * (float)KNN_G));

  unsigned long long k16[16];
#pragma unroll
  for (int s = 0; s < 16; ++s) k16[s] = ~0ull;
  unsigned long long worst = ~0ull;
  int wslot = 0;

  auto proc = [&](const float4 q, const int oj) {
    if (oj == i) return;
    const float a0 = q.x - tx, a1 = q.y - ty, a2 = q.z - tz, a3 = q.w - tw;
    const float s0 = a0*a0, s1 = a1*a1, s2 = a2*a2, s3 = a3*a3;
    const float d = ((s0 + s1) + s2) + s3;
    const unsigned long long key =
        ((unsigned long long)__float_as_uint(d) << 32) | (unsigned)oj;
    if (key < worst) {
#pragma unroll
      for (int s = 0; s < 16; ++s) if (s == wslot) k16[s] = key;
      worst = k16[0]; wslot = 0;
#pragma unroll
      for (int s = 1; s < 16; ++s)
        if (k16[s] > worst) { worst = k16[s]; wslot = s; }
    }
  };

  auto cell = [&](const int cid) {
    const int s = cellstart[cid], e = cellstart[cid+1];
    int p = s;
    for (; p + 1 < e; p += 2) {        // 2-wide: overlap the two loads
      const float4 qa = *(const float4*)(locs4s + (size_t)p*4);
      const int    ja = oidx[p];
      const float4 qb = *(const float4*)(locs4s + (size_t)(p+1)*4);
      const int    jb = oidx[p+1];
      proc(qa, ja);
      proc(qb, jb);
    }
    if (p < e) proc(*(const float4*)(locs4s + (size_t)p*4), oidx[p]);
  };

  // shell 0
  cell(((cx*KNN_G + cy)*KNN_G + cz)*KNN_G + cw);
  // shells 1..G-1 with early termination
  for (int m = 1; m < KNN_G; ++m) {
    if (worst != ~0ull) {
      const float tau = __uint_as_float((unsigned)(worst >> 32));
      const float lb = (float)(m - 1) * (1.0f / (float)KNN_G);
      if (tau < lb * lb * 0.99999f) break;
    }
    const int xlo = max(cx-m, 0), xhi = min(cx+m, KNN_G-1);
    for (int ax = xlo; ax <= xhi; ++ax) {
      const bool xe = (ax == cx-m) || (ax == cx+m);
      const int ylo = max(cy-m, 0), yhi = min(cy+m, KNN_G-1);
      for (int ay = ylo; ay <= yhi; ++ay) {
        const bool ye = (ay == cy-m) || (ay == cy+m);
        const int zlo = max(cz-m, 0), zhi = min(cz+m, KNN_G-1);
        for (int az = zlo; az <= zhi; ++az) {
          const bool ze = (az == cz-m) || (az == cz+m);
          const int base = ((ax*KNN_G + ay)*KNN_G + az)*KNN_G;
          if (xe | ye | ze) {
            const int wl = max(cw-m, 0), wh = min(cw+m, KNN_G-1);
            for (int aw = wl; aw <= wh; ++aw) cell(base + aw);
          } else {
            if (cw-m >= 0)       cell(base + cw - m);
            if (cw+m <= KNN_G-1) cell(base + cw + m);
          }
        }
      }
    }
  }

#pragma unroll
  for (int s = 0; s < 16; ++s)
    knn[(size_t)i*16 + s] = (int)(k16[s] & 0xFFFFFFFFull);
}

// ---------------------------------------------------------------------------
// Single-block exclusive scan (out[0..n-1] = excl prefix, out[n] = total).
// 1024 threads, each owns a serial chunk of `per` elements.
// ---------------------------------------------------------------------------
__global__ __launch_bounds__(1024) void scan1b_kernel(
    const int* __restrict__ in, int* __restrict__ out, int n, int per)
{
  __shared__ int part[1024];
  const int t = threadIdx.x;
  const int lo = t * per, hi = min(lo + per, n);
  int sum = 0;
  for (int idx = lo; idx < hi; ++idx) sum += in[idx];
  int v = sum;
  part[t] = v;
  __syncthreads();
  for (int off = 1; off < 1024; off <<= 1) {
    const int o = (t >= off) ? part[t - off] : 0;
    __syncthreads();
    v += o;
    part[t] = v;
    __syncthreads();
  }
  int run = v - sum;
  for (int idx = lo; idx < hi; ++idx) { out[idx] = run; run += in[idx]; }
  if (t == 1023) out[n] = v;
}

// ---------------------------------------------------------------------------
// Static-graph CSR build (dst-grouped), atomic-free consumption afterwards.
// ---------------------------------------------------------------------------
__global__ __launch_bounds__(256) void deg_kernel(const int* __restrict__ dst,
                                                  int* __restrict__ deg, int E)
{
  const int e = blockIdx.x * 256 + threadIdx.x;
  if (e < E) atomicAdd(&deg[dst[e]], 1);
}

__global__ __launch_bounds__(256) void csr_scatter_kernel(
    const int* __restrict__ srcs, const int* __restrict__ dsts,
    const int* __restrict__ rowptr, int* __restrict__ dfill,
    int* __restrict__ cs_src, int* __restrict__ cs_eid, int E)
{
  const int e = blockIdx.x * 256 + threadIdx.x;
  if (e < E) {
    const int d = dsts[e];
    const int pos = rowptr[d] + atomicAdd(&dfill[d], 1);
    cs_src[pos] = srcs[e];
    cs_eid[pos] = e;
  }
}

// ---------------------------------------------------------------------------
// Static conv message + segment max. One dst per wave (4/block), lane =
// output channel, registers-only max, coalesced write. Empty segment -> 0.
// ---------------------------------------------------------------------------
__global__ __launch_bounds__(256) void static_msg_kernel(
    const float* __restrict__ R, const float* __restrict__ ea,
    const float* __restrict__ wm, const float* __restrict__ bm,
    const int* __restrict__ cs_src, const int* __restrict__ cs_eid,
    const int* __restrict__ rowptr, float* __restrict__ agg, int n)
{
  __shared__ float wma[64][17];   // cols 0..15 of wm, padded
  for (int idx = threadIdx.x; idx < 1024; idx += 256) {
    const int r = idx >> 4, cc = idx & 15;
    wma[r][cc] = wm[r*80 + cc];
  }
  __syncthreads();
  const int wave = threadIdx.x >> 6, lane = threadIdx.x & 63;
  const int d = blockIdx.x * 4 + wave;
  if (d >= n) return;
  const int beg = rowptr[d], end = rowptr[d+1];
  const float base = bm[lane] - R[(size_t)d*64 + lane];
  const float* wr = wma[lane];
  float vmax = 0.f;
  for (int p = beg; p < end; ++p) {
    const int s = cs_src[p];
    const int e = cs_eid[p];
    float acc = base + R[(size_t)s*64 + lane];
    const float4* e4 = (const float4*)(ea + (size_t)e*16);
    const float4 q0 = e4[0], q1 = e4[1], q2 = e4[2], q3 = e4[3];
    acc = fmaf(q0.x, wr[0],  acc); acc = fmaf(q0.y, wr[1],  acc);
    acc = fmaf(q0.z, wr[2],  acc); acc = fmaf(q0.w, wr[3],  acc);
    acc = fmaf(q1.x, wr[4],  acc); acc = fmaf(q1.y, wr[5],  acc);
    acc = fmaf(q1.z, wr[6],  acc); acc = fmaf(q1.w, wr[7],  acc);
    acc = fmaf(q2.x, wr[8],  acc); acc = fmaf(q2.y, wr[9],  acc);
    acc = fmaf(q2.z, wr[10], acc); acc = fmaf(q2.w, wr[11], acc);
    acc = fmaf(q3.x, wr[12], acc); acc = fmaf(q3.y, wr[13], acc);
    acc = fmaf(q3.z, wr[14], acc); acc = fmaf(q3.w, wr[15], acc);
    vmax = fmaxf(vmax, acc);    // == max(vmax, relu(acc)) since vmax >= 0
  }
  agg[(size_t)d*64 + lane] = vmax;
}

// ---------------------------------------------------------------------------
// Pack dyn-layer weights: Wpq[256][64] = [w1a - w1b ; w1b], bpq = [b1 ; 0].
// P||Q = h @ Wpq^T + bpq, then t_e = relu(P[i] + Q[j]).
// ---------------------------------------------------------------------------
__global__ __launch_bounds__(256) void pack_kernel(const float* __restrict__ w1,
                                                   const float* __restrict__ b1,
                                                   float* __restrict__ wpq,
                                                   float* __restrict__ bpq)
{
  const int idx = blockIdx.x * 256 + threadIdx.x;
  if (idx < 128 * 64) {
    const int o = idx >> 6, i = idx & 63;
    const float a = w1[o*128 + i], b = w1[o*128 + 64 + i];
    wpq[idx] = a - b;               // P rows 0..127
    wpq[128*64 + idx] = b;          // Q rows 128..255
  }
  if (idx < 128) { bpq[idx] = b1[idx]; bpq[128 + idx] = 0.f; }
}

// ---------------------------------------------------------------------------
// Generic fp32 linear: C[M][cols] = act(A[M][K] @ W[cols][K]^T + bias)
// block = 256 threads (4 waves x 8 rows), tile 32 rows x 64 cols, K-step 64.
// W staged float4-transposed [Kgroup][channel] -> conflict-free b128 reads.
// ---------------------------------------------------------------------------
template<bool RELU, bool ACC>
__global__ __launch_bounds__(256) void linear_kernel(
    const float* __restrict__ A, int lda,
    const float* __restrict__ W, int ldw,
    const float* __restrict__ bias,
    float* __restrict__ C, int ldc, int M, int K)
{
  __shared__ float As[32 * 64];
  __shared__ float Ws[16 * 64 * 4];   // [g][c] float4, g = K/4 group
  const int m0 = blockIdx.x * 32;
  const int c0 = blockIdx.y * 64;
  const int tid = threadIdx.x;
  const int wave = tid >> 6, lane = tid & 63;
  const int c = c0 + lane;

  float acc[8];
#pragma unroll
  for (int t = 0; t < 8; ++t) acc[t] = 0.f;

  for (int kt = 0; kt < K; kt += 64) {
    // stage A tile [32][64] (coalesced)
    {
      int idx = tid;
#pragma unroll
      for (int itr = 0; itr < 2; ++itr, idx += 256) {
        const int row = idx >> 4, col4 = idx & 15;
        const int gr = m0 + row;
        float4 v = make_float4(0.f, 0.f, 0.f, 0.f);
        if (gr < M) v = *(const float4*)(A + (size_t)gr*lda + kt + col4*4);
        *(float4*)(As + row*64 + col4*4) = v;
      }
      // stage W tile f4-transposed: slot idx = g*64 + ch
      idx = tid;
#pragma unroll
      for (int itr = 0; itr < 4; ++itr, idx += 256) {
        const int ch = idx & 63, g = idx >> 6;
        const float4 v = *(const float4*)(W + (size_t)(c0 + ch)*ldw + kt + g*4);
        *(float4*)(Ws + idx*4) = v;
      }
    }
    __syncthreads();
    const float* ar = As + wave*8*64;
    for (int g = 0; g < 16; ++g) {
      const float4 w = *(const float4*)(Ws + (g*64 + lane)*4);  // conflict-free
#pragma unroll
      for (int t = 0; t < 8; ++t) {
        const float4 a = *(const float4*)(ar + t*64 + g*4);     // broadcast
        acc[t] = fmaf(w.x, a.x, fmaf(w.y, a.y, fmaf(w.z, a.z, fmaf(w.w, a.w, acc[t]))));
      }
    }
    __syncthreads();
  }

  const float b = bias ? bias[c] : 0.f;
#pragma unroll
  for (int t = 0; t < 8; ++t) {
    const int gr = m0 + wave*8 + t;
    if (gr < M) {
      float v = acc[t] + b;
      if (RELU) v = fmaxf(v, 0.f);
      float* cp = C + (size_t)gr*ldc + c;
      if (ACC) v += *cp;
      *cp = v;
    }
  }
}

// ---------------------------------------------------------------------------
// Dynamic conv: per target i, 17 neighbors (16 kNN + self).
// t_e = relu(P[i] + Q[j]); out[i][c] = relu(max_e (t_e . W2[c]) + b2[c]).
// W2 staged f4-transposed [g][c] -> conflict-free b128; T reads broadcast.
// ---------------------------------------------------------------------------
template<int NB>
__device__ __forceinline__ float dyn_block(
    int i, int nb0, const int* __restrict__ knn,
    const float* __restrict__ PQ,
    const float* __restrict__ w2s, float* __restrict__ Tw,
    int lane, float vmax)
{
  for (int idx = lane; idx < NB * 32; idx += 64) {
    const int off = idx << 2;
    const int nb = off >> 7, kk = off & 127;
    const int nbg = nb0 + nb;
    const int j = (nbg < 16) ? knn[(size_t)i*16 + nbg] : i;
    const float4 p = *(const float4*)(PQ + (size_t)i*256 + kk);
    const float4 q = *(const float4*)(PQ + (size_t)j*256 + 128 + kk);
    float4 t;
    t.x = fmaxf(p.x + q.x, 0.f); t.y = fmaxf(p.y + q.y, 0.f);
    t.z = fmaxf(p.z + q.z, 0.f); t.w = fmaxf(p.w + q.w, 0.f);
    *(float4*)(Tw + off) = t;
  }
  __syncthreads();
  float acc[NB];
#pragma unroll
  for (int t = 0; t < NB; ++t) acc[t] = 0.f;
  for (int g = 0; g < 32; ++g) {
    const float4 w = *(const float4*)(w2s + (g*64 + lane)*4);   // conflict-free
#pragma unroll
    for (int t = 0; t < NB; ++t) {
      const float4 tv = *(const float4*)(Tw + t*128 + g*4);     // broadcast
      acc[t] = fmaf(w.x, tv.x, fmaf(w.y, tv.y, fmaf(w.z, tv.z, fmaf(w.w, tv.w, acc[t]))));
    }
  }
#pragma unroll
  for (int t = 0; t < NB; ++t) vmax = fmaxf(vmax, acc[t]);
  return vmax;
}

__global__ __launch_bounds__(256) void dyn_conv_kernel(
    const float* __restrict__ PQ,
    const float* __restrict__ W2, const float* __restrict__ b2,
    const int* __restrict__ knn, float* __restrict__ out, int ldo, int n)
{
  __shared__ float w2s[32 * 64 * 4];   // [g][c] float4 of W2 rows
  __shared__ float T[4][1152];         // per-wave [9][128]
  for (int idx = threadIdx.x; idx < 2048; idx += 256) {
    const int ch = idx & 63, g = idx >> 6;
    *(float4*)(w2s + idx*4) = *(const float4*)(W2 + (size_t)ch*128 + g*4);
  }
  __syncthreads();
  const int wave = threadIdx.x >> 6, lane = threadIdx.x & 63;
  const int i = blockIdx.x * 4 + wave;
  float vmax = -INF_F;
  vmax = dyn_block<9>(i, 0, knn, PQ, w2s, T[wave], lane, vmax);
  vmax = dyn_block<8>(i, 9, knn, PQ, w2s, T[wave], lane, vmax);
  if (i < n) out[(size_t)i*ldo + lane] = fmaxf(vmax + b2[lane], 0.f);
}

// ---------------------------------------------------------------------------
// Host orchestration
// ---------------------------------------------------------------------------
extern "C" void kernel_launch(void* const* d_in, const int* in_sizes, int n_in,
                              void* d_out, int out_size, void* d_ws, size_t ws_size,
                              hipStream_t stream)
{
  const float* x   = (const float*)d_in[0];
  const int*   ei  = (const int*)d_in[1];
  const float* ea  = (const float*)d_in[2];
  const float* loc = (const float*)d_in[3];
  const float* sg_wm[3] = {(const float*)d_in[5],  (const float*)d_in[9],  (const float*)d_in[13]};
  const float* sg_bm[3] = {(const float*)d_in[6],  (const float*)d_in[10], (const float*)d_in[14]};
  const float* sg_wu[3] = {(const float*)d_in[7],  (const float*)d_in[11], (const float*)d_in[15]};
  const float* sg_bu[3] = {(const float*)d_in[8],  (const float*)d_in[12], (const float*)d_in[16]};
  const float* dg_w1[2] = {(const float*)d_in[17], (const float*)d_in[21]};
  const float* dg_b1[2] = {(const float*)d_in[18], (const float*)d_in[22]};
  const float* dg_w2[2] = {(const float*)d_in[19], (const float*)d_in[23]};
  const float* dg_b2[2] = {(const float*)d_in[20], (const float*)d_in[24]};
  const float* f1_w = (const float*)d_in[25];
  const float* f1_b = (const float*)d_in[26];
  const float* f2_w = (const float*)d_in[27];
  const float* f2_b = (const float*)d_in[28];
  float* out = (float*)d_out;

  const int n    = in_sizes[0] / 64;
  const int Etot = in_sizes[1] / 2;
  const int* srcp = ei;
  const int* dstp = ei + Etot;

  char* basep = (char*)d_ws;
  size_t cur = 0;
  auto alloc = [&](size_t bytes) -> void* {
    void* p = basep + cur;
    cur = (cur + bytes + 255) & ~(size_t)255;
    return p;
  };
  float* CAT  = (float*)alloc((size_t)n * 320 * 4);
  float* Rb   = (float*)alloc((size_t)n * 64 * 4);
  float* PQb  = (float*)alloc((size_t)n * 256 * 4);
  float* agg  = (float*)alloc((size_t)n * 64 * 4);
  float* fu1  = (float*)alloc((size_t)n * 64 * 4);
  float* wpq[2];
  float* bpq[2];
  wpq[0] = (float*)alloc(256 * 64 * 4);  bpq[0] = (float*)alloc(256 * 4);
  wpq[1] = (float*)alloc(256 * 64 * 4);  bpq[1] = (float*)alloc(256 * 4);
  int* knnb   = (int*)alloc((size_t)n * 16 * 4);
  // zero region: [cellcount 1296][cellfill 1296][deg n][dfill n]
  int* zeros     = (int*)alloc((size_t)(2*KNN_NC + 2*n) * 4);
  int* cellcount = zeros;
  int* cellfill  = zeros + KNN_NC;
  int* deg       = zeros + 2*KNN_NC;
  int* dfill     = zeros + 2*KNN_NC + n;
  int* cellstart = (int*)alloc((size_t)(KNN_NC + 1) * 4);
  int* cellidb   = (int*)alloc((size_t)n * 4);
  float* locs4s  = (float*)alloc((size_t)n * 4 * 4);
  int* oidx      = (int*)alloc((size_t)n * 4);
  int* rowptr    = (int*)alloc((size_t)(n + 1) * 4);
  int* cs_src    = (int*)alloc((size_t)Etot * 4);
  int* cs_eid    = (int*)alloc((size_t)Etot * 4);
  (void)ws_size; (void)n_in; (void)out_size;

  const int nb256 = (n + 255) / 256;

  hipMemsetAsync(zeros, 0, (size_t)(2*KNN_NC + 2*n) * 4, stream);
  // kNN bin build + query
  bin_count_kernel<<<nb256, 256, 0, stream>>>(loc, cellcount, cellidb, n);
  scan1b_kernel<<<1, 1024, 0, stream>>>(cellcount, cellstart, KNN_NC,
                                        (KNN_NC + 1023) / 1024);
  bin_scatter_kernel<<<nb256, 256, 0, stream>>>(loc, cellidb, cellstart,
                                                cellfill, locs4s, oidx, n);
  knn_binned_kernel<<<nb256, 256, 0, stream>>>(locs4s, oidx, cellstart, knnb, n);
  // static CSR build
  deg_kernel<<<(Etot + 255) / 256, 256, 0, stream>>>(dstp, deg, Etot);
  scan1b_kernel<<<1, 1024, 0, stream>>>(deg, rowptr, n, (n + 1023) / 1024);
  csr_scatter_kernel<<<(Etot + 255) / 256, 256, 0, stream>>>(
      srcp, dstp, rowptr, dfill, cs_src, cs_eid, Etot);
  // dyn weight packing
  pack_kernel<<<32, 256, 0, stream>>>(dg_w1[0], dg_b1[0], wpq[0], bpq[0]);
  pack_kernel<<<32, 256, 0, stream>>>(dg_w1[1], dg_b1[1], wpq[1], bpq[1]);

  const int mb = (n + 31) / 32;
  auto lin = [&](const float* A, int lda, const float* W, int ldw, const float* bias,
                 float* C, int ldc, int K, int ncols, bool relu, bool accum) {
    dim3 grid(mb, ncols / 64);
    if (relu)       linear_kernel<true,  false><<<grid, 256, 0, stream>>>(A, lda, W, ldw, bias, C, ldc, n, K);
    else if (accum) linear_kernel<false, true ><<<grid, 256, 0, stream>>>(A, lda, W, ldw, bias, C, ldc, n, K);
    else            linear_kernel<false, false><<<grid, 256, 0, stream>>>(A, lda, W, ldw, bias, C, ldc, n, K);
  };

  // static layers: x -> h1(CAT+0) -> h2(CAT+192) -> h3(CAT+256)
  const float* hin = x; int hlda = 64;
  float* hout[3] = {CAT + 0, CAT + 192, CAT + 256};
  for (int l = 0; l < 3; ++l) {
    lin(hin, hlda, sg_wm[l] + 16, 80, nullptr, Rb, 64, 64, 64, false, false);
    static_msg_kernel<<<(n + 3) / 4, 256, 0, stream>>>(Rb, ea, sg_wm[l], sg_bm[l],
                                                       cs_src, cs_eid, rowptr, agg, n);
    lin(agg, 64, sg_wu[l], 64, sg_bu[l], hout[l], 320, 64, 64, true, false);
    hin = hout[l]; hlda = 320;
  }

  // dynamic layers: h1 -> g1(CAT+64); g1 -> g2(CAT+128)
  const float* din[2] = {CAT + 0, CAT + 64};
  float* doutp[2] = {CAT + 64, CAT + 128};
  for (int l = 0; l < 2; ++l) {
    lin(din[l], 320, wpq[l], 64, bpq[l], PQb, 256, 64, 256, false, false);
    dyn_conv_kernel<<<(n + 3) / 4, 256, 0, stream>>>(PQb, dg_w2[l], dg_b2[l],
                                                     knnb, doutp[l], 320, n);
  }

  // fusion
  lin(CAT, 320, f1_w, 320, f1_b, fu1, 64, 320, 64, true,  false);
  lin(CAT, 320, f2_w + 64, 384, f2_b, out, 64, 320, 64, false, false);
  lin(fu1, 64, f2_w, 384, nullptr, out, 64, 64, 64, false, true);
}

// Round 5
// 643.760 us; speedup vs baseline: 2.2996x; 2.2996x over previous
//
#include <hip/hip_runtime.h>

#define INF_F __builtin_inff()

// ===========================================================================
// Spatial-bin exact kNN, WAVE-per-target.
// Grid 4^4 over [0,1]^4; counting-sort points by cell. Each wave owns one
// target and scans the radius-1 Chebyshev block (then rare shells m=2,3)
// 64 candidates per chunk, with threshold-tau ballot-compaction appends into
// a per-wave LDS buffer and a 16-round wave-argmin refine (round-2 machinery,
// no LDS atomics).
// Key = (dist_bits<<32)|orig_j : u64 ascending == (dist, index) lexicographic
// == reference top_k order (dist >= 0, orig indices unique -> keys unique).
// Exactness: tau after a refine is the exact 16th-smallest key seen; stale
// tau between refines is only LARGER (conservative). After the radius-r
// region is complete, any unseen point has true d^2 > (r/G)^2 (strict), so
// breaking when tau < (r/G)^2*(1-1e-5) cannot discard a true top-16 member.
// Distance arithmetic matches the reference bit-for-bit: contract off,
// separately rounded squares, sequential sum.
// ===========================================================================
#define KNN_G 4
#define KNN_NC (KNN_G*KNN_G*KNN_G*KNN_G)   // 256

__global__ __launch_bounds__(256) void bin_count_kernel(
    const float* __restrict__ loc, int* __restrict__ cellcount,
    int* __restrict__ cellid, int n)
{
  const int i = blockIdx.x * 256 + threadIdx.x;
  if (i >= n) return;
  const float4 l = *(const float4*)(loc + (size_t)i*4);
  const int cx = min(KNN_G-1, (int)(l.x * (float)KNN_G));
  const int cy = min(KNN_G-1, (int)(l.y * (float)KNN_G));
  const int cz = min(KNN_G-1, (int)(l.z * (float)KNN_G));
  const int cw = min(KNN_G-1, (int)(l.w * (float)KNN_G));
  const int c = ((cx*KNN_G + cy)*KNN_G + cz)*KNN_G + cw;
  cellid[i] = c;
  atomicAdd(&cellcount[c], 1);
}

__global__ __launch_bounds__(256) void bin_scatter_kernel(
    const float* __restrict__ loc, const int* __restrict__ cellid,
    const int* __restrict__ cellstart, int* __restrict__ cellfill,
    float* __restrict__ locs4s, int* __restrict__ oidx, int n)
{
  const int i = blockIdx.x * 256 + threadIdx.x;
  if (i >= n) return;
  const int c = cellid[i];
  const int pos = cellstart[c] + atomicAdd(&cellfill[c], 1);
  *(float4*)(locs4s + (size_t)pos*4) = *(const float4*)(loc + (size_t)i*4);
  oidx[pos] = i;
}

__device__ __forceinline__ unsigned long long
knn_refine16(unsigned long long* __restrict__ B, int cnt, int lane,
             unsigned long long& topsave)
{
  unsigned long long v[5];
#pragma unroll
  for (int s = 0; s < 5; ++s) {
    const int idx = lane + 64*s;
    v[s] = (idx < cnt) ? B[idx] : ~0ull;
  }
  unsigned long long tau = ~0ull;
#pragma unroll
  for (int r = 0; r < 16; ++r) {
    unsigned long long m = v[0]; int sl = 0;
#pragma unroll
    for (int s = 1; s < 5; ++s) if (v[s] < m) { m = v[s]; sl = s; }
    unsigned long long mm = m;
#pragma unroll
    for (int off = 32; off >= 1; off >>= 1) {
      const unsigned long long o = __shfl_xor(mm, off, 64);
      if (o < mm) mm = o;
    }
    const bool killer = (m == mm);
#pragma unroll
    for (int s = 0; s < 5; ++s) if (killer && sl == s) v[s] = ~0ull;
    if (lane == r) topsave = mm;
    tau = mm;            // after round 15: exact 16th-smallest
  }
  if (lane < 16) B[lane] = topsave;
  return tau;
}

__global__ __launch_bounds__(256) void knn_wave_kernel(
    const float* __restrict__ locs4s, const int* __restrict__ oidx,
    const int* __restrict__ cellstart, int* __restrict__ knn, int n)
{
#pragma clang fp contract(off)
  constexpr int CAP = 320, TRIG = 256;   // per-chunk appends <= 64 -> cnt <= 320
  __shared__ unsigned long long Bs[4][CAP];
  const int wave = threadIdx.x >> 6, lane = threadIdx.x & 63;
  const int t = blockIdx.x * 4 + wave;   // sorted position of target
  if (t >= n) return;
  unsigned long long* B = Bs[wave];

  const float4 L = *(const float4*)(locs4s + (size_t)t*4);
  const float tx = L.x, ty = L.y, tz = L.z, tw = L.w;
  const int cx = min(KNN_G-1, (int)(tx * (float)KNN_G));
  const int cy = min(KNN_G-1, (int)(ty * (float)KNN_G));
  const int cz = min(KNN_G-1, (int)(tz * (float)KNN_G));
  const int cw = min(KNN_G-1, (int)(tw * (float)KNN_G));

  unsigned long long tau = ~0ull;        // current 16th-best key (wave-uniform)
  unsigned long long topsave = ~0ull;
  int cnt = 0;

  auto do_range = [&](int ps, int pe) {
    for (int p0 = ps; p0 < pe; p0 += 64) {
      const int p = p0 + lane;
      unsigned long long key = ~0ull;
      if (p < pe && p != t) {
        const float4 q = *(const float4*)(locs4s + (size_t)p*4);
        const int oj = oidx[p];
        const float a0 = q.x - tx, a1 = q.y - ty, a2 = q.z - tz, a3 = q.w - tw;
        const float s0 = a0*a0, s1 = a1*a1, s2 = a2*a2, s3 = a3*a3;
        const float d = ((s0 + s1) + s2) + s3;
        key = ((unsigned long long)__float_as_uint(d) << 32) | (unsigned)oj;
      }
      const bool surv = key < tau;
      const unsigned long long mask = __ballot(surv);
      if (mask) {
        const unsigned pre = __builtin_amdgcn_mbcnt_hi(
            (unsigned)(mask >> 32),
            __builtin_amdgcn_mbcnt_lo((unsigned)mask, 0u));
        if (surv) B[cnt + pre] = key;
        cnt += (int)__popcll(mask);
        if (cnt > TRIG) { tau = knn_refine16(B, cnt, lane, topsave); cnt = 16; }
      }
    }
  };

  // ---- level 0: radius-1 block. Lane r<27 prefetches combo r's range. ----
  int psv = 0, pev = 0;
  if (lane < 27) {
    const int ax = cx + (lane / 9) - 1;
    const int ay = cy + ((lane / 3) % 3) - 1;
    const int az = cz + (lane % 3) - 1;
    if (ax >= 0 && ax < KNN_G && ay >= 0 && ay < KNN_G &&
        az >= 0 && az < KNN_G) {
      const int base = ((ax*KNN_G + ay)*KNN_G + az)*KNN_G;
      const int wlo = max(cw-1, 0), whi = min(cw+1, KNN_G-1);
      psv = cellstart[base + wlo];
      pev = cellstart[base + whi + 1];
    }
  }
  for (int r = 0; r < 27; ++r) {
    const int ps = __shfl(psv, r, 64);
    const int pe = __shfl(pev, r, 64);
    if (ps < pe) do_range(ps, pe);
  }

  // ---- shells m = 2..G-1 (rare: near-corner targets) ----
  for (int m = 2; m <= KNN_G - 1; ++m) {
    if (cnt > 16) { tau = knn_refine16(B, cnt, lane, topsave); cnt = 16; }
    if (tau != ~0ull) {
      const float taud = __uint_as_float((unsigned)(tau >> 32));
      const float r = (float)(m - 1) * (1.0f / (float)KNN_G);
      if (taud < r * r * 0.99999f) break;
    }
    const int xlo = max(cx-m, 0), xhi = min(cx+m, KNN_G-1);
    for (int ax = xlo; ax <= xhi; ++ax) {
      const bool xe = (ax == cx-m) || (ax == cx+m);
      const int ylo = max(cy-m, 0), yhi = min(cy+m, KNN_G-1);
      for (int ay = ylo; ay <= yhi; ++ay) {
        const bool ye = (ay == cy-m) || (ay == cy+m);
        const int zlo = max(cz-m, 0), zhi = min(cz+m, KNN_G-1);
        for (int az = zlo; az <= zhi; ++az) {
          const bool ze = (az == cz-m) || (az == cz+m);
          const int base = ((ax*KNN_G + ay)*KNN_G + az)*KNN_G;
          if (xe | ye | ze) {
            const int wlo = max(cw-m, 0), whi = min(cw+m, KNN_G-1);
            do_range(cellstart[base+wlo], cellstart[base+whi+1]);
          } else {
            if (cw-m >= 0) {
              const int c = base + cw - m;
              do_range(cellstart[c], cellstart[c+1]);
            }
            if (cw+m <= KNN_G-1) {
              const int c = base + cw + m;
              do_range(cellstart[c], cellstart[c+1]);
            }
          }
        }
      }
    }
  }
  if (cnt > 16) (void)knn_refine16(B, cnt, lane, topsave);
  const int i = oidx[t];
  if (lane < 16) knn[(size_t)i*16 + lane] = (int)(topsave & 0xFFFFFFFFull);
}

// ---------------------------------------------------------------------------
// Single-block exclusive scan (out[0..n-1] = excl prefix, out[n] = total).
// ---------------------------------------------------------------------------
__global__ __launch_bounds__(1024) void scan1b_kernel(
    const int* __restrict__ in, int* __restrict__ out, int n, int per)
{
  __shared__ int part[1024];
  const int t = threadIdx.x;
  const int lo = t * per, hi = min(lo + per, n);
  int sum = 0;
  for (int idx = lo; idx < hi; ++idx) sum += in[idx];
  int v = sum;
  part[t] = v;
  __syncthreads();
  for (int off = 1; off < 1024; off <<= 1) {
    const int o = (t >= off) ? part[t - off] : 0;
    __syncthreads();
    v += o;
    part[t] = v;
    __syncthreads();
  }
  int run = v - sum;
  for (int idx = lo; idx < hi; ++idx) { out[idx] = run; run += in[idx]; }
  if (t == 1023) out[n] = v;
}

// ---------------------------------------------------------------------------
// Static-graph CSR build (dst-grouped), atomic-free consumption afterwards.
// ---------------------------------------------------------------------------
__global__ __launch_bounds__(256) void deg_kernel(const int* __restrict__ dst,
                                                  int* __restrict__ deg, int E)
{
  const int e = blockIdx.x * 256 + threadIdx.x;
  if (e < E) atomicAdd(&deg[dst[e]], 1);
}

__global__ __launch_bounds__(256) void csr_scatter_kernel(
    const int* __restrict__ srcs, const int* __restrict__ dsts,
    const int* __restrict__ rowptr, int* __restrict__ dfill,
    int* __restrict__ cs_src, int* __restrict__ cs_eid, int E)
{
  const int e = blockIdx.x * 256 + threadIdx.x;
  if (e < E) {
    const int d = dsts[e];
    const int pos = rowptr[d] + atomicAdd(&dfill[d], 1);
    cs_src[pos] = srcs[e];
    cs_eid[pos] = e;
  }
}

// ---------------------------------------------------------------------------
// Static conv message + segment max. One dst per wave (4/block), lane =
// output channel, registers-only max, coalesced write. Empty segment -> 0.
// ---------------------------------------------------------------------------
__global__ __launch_bounds__(256) void static_msg_kernel(
    const float* __restrict__ R, const float* __restrict__ ea,
    const float* __restrict__ wm, const float* __restrict__ bm,
    const int* __restrict__ cs_src, const int* __restrict__ cs_eid,
    const int* __restrict__ rowptr, float* __restrict__ agg, int n)
{
  __shared__ float wma[64][17];   // cols 0..15 of wm, padded
  for (int idx = threadIdx.x; idx < 1024; idx += 256) {
    const int r = idx >> 4, cc = idx & 15;
    wma[r][cc] = wm[r*80 + cc];
  }
  __syncthreads();
  const int wave = threadIdx.x >> 6, lane = threadIdx.x & 63;
  const int d = blockIdx.x * 4 + wave;
  if (d >= n) return;
  const int beg = rowptr[d], end = rowptr[d+1];
  const float base = bm[lane] - R[(size_t)d*64 + lane];
  const float* wr = wma[lane];
  float vmax = 0.f;
  for (int p = beg; p < end; ++p) {
    const int s = cs_src[p];
    const int e = cs_eid[p];
    float acc = base + R[(size_t)s*64 + lane];
    const float4* e4 = (const float4*)(ea + (size_t)e*16);
    const float4 q0 = e4[0], q1 = e4[1], q2 = e4[2], q3 = e4[3];
    acc = fmaf(q0.x, wr[0],  acc); acc = fmaf(q0.y, wr[1],  acc);
    acc = fmaf(q0.z, wr[2],  acc); acc = fmaf(q0.w, wr[3],  acc);
    acc = fmaf(q1.x, wr[4],  acc); acc = fmaf(q1.y, wr[5],  acc);
    acc = fmaf(q1.z, wr[6],  acc); acc = fmaf(q1.w, wr[7],  acc);
    acc = fmaf(q2.x, wr[8],  acc); acc = fmaf(q2.y, wr[9],  acc);
    acc = fmaf(q2.z, wr[10], acc); acc = fmaf(q2.w, wr[11], acc);
    acc = fmaf(q3.x, wr[12], acc); acc = fmaf(q3.y, wr[13], acc);
    acc = fmaf(q3.z, wr[14], acc); acc = fmaf(q3.w, wr[15], acc);
    vmax = fmaxf(vmax, acc);    // == max(vmax, relu(acc)) since vmax >= 0
  }
  agg[(size_t)d*64 + lane] = vmax;
}

// ---------------------------------------------------------------------------
// Pack dyn-layer weights: Wpq[256][64] = [w1a - w1b ; w1b], bpq = [b1 ; 0].
// P||Q = h @ Wpq^T + bpq, then t_e = relu(P[i] + Q[j]).
// ---------------------------------------------------------------------------
__global__ __launch_bounds__(256) void pack_kernel(const float* __restrict__ w1,
                                                   const float* __restrict__ b1,
                                                   float* __restrict__ wpq,
                                                   float* __restrict__ bpq)
{
  const int idx = blockIdx.x * 256 + threadIdx.x;
  if (idx < 128 * 64) {
    const int o = idx >> 6, i = idx & 63;
    const float a = w1[o*128 + i], b = w1[o*128 + 64 + i];
    wpq[idx] = a - b;               // P rows 0..127
    wpq[128*64 + idx] = b;          // Q rows 128..255
  }
  if (idx < 128) { bpq[idx] = b1[idx]; bpq[128 + idx] = 0.f; }
}

// ---------------------------------------------------------------------------
// Generic fp32 linear: C[M][cols] = act(A[M][K] @ W[cols][K]^T + bias)
// block = 256 threads (4 waves x 8 rows), tile 32 rows x 64 cols, K-step 64.
// W staged float4-transposed [Kgroup][channel] -> conflict-free b128 reads.
// ---------------------------------------------------------------------------
template<bool RELU, bool ACC>
__global__ __launch_bounds__(256) void linear_kernel(
    const float* __restrict__ A, int lda,
    const float* __restrict__ W, int ldw,
    const float* __restrict__ bias,
    float* __restrict__ C, int ldc, int M, int K)
{
  __shared__ float As[32 * 64];
  __shared__ float Ws[16 * 64 * 4];   // [g][c] float4, g = K/4 group
  const int m0 = blockIdx.x * 32;
  const int c0 = blockIdx.y * 64;
  const int tid = threadIdx.x;
  const int wave = tid >> 6, lane = tid & 63;
  const int c = c0 + lane;

  float acc[8];
#pragma unroll
  for (int t = 0; t < 8; ++t) acc[t] = 0.f;

  for (int kt = 0; kt < K; kt += 64) {
    // stage A tile [32][64] (coalesced)
    {
      int idx = tid;
#pragma unroll
      for (int itr = 0; itr < 2; ++itr, idx += 256) {
        const int row = idx >> 4, col4 = idx & 15;
        const int gr = m0 + row;
        float4 v = make_float4(0.f, 0.f, 0.f, 0.f);
        if (gr < M) v = *(const float4*)(A + (size_t)gr*lda + kt + col4*4);
        *(float4*)(As + row*64 + col4*4) = v;
      }
      // stage W tile f4-transposed: slot idx = g*64 + ch
      idx = tid;
#pragma unroll
      for (int itr = 0; itr < 4; ++itr, idx += 256) {
        const int ch = idx & 63, g = idx >> 6;
        const float4 v = *(const float4*)(W + (size_t)(c0 + ch)*ldw + kt + g*4);
        *(float4*)(Ws + idx*4) = v;
      }
    }
    __syncthreads();
    const float* ar = As + wave*8*64;
    for (int g = 0; g < 16; ++g) {
      const float4 w = *(const float4*)(Ws + (g*64 + lane)*4);  // conflict-free
#pragma unroll
      for (int t = 0; t < 8; ++t) {
        const float4 a = *(const float4*)(ar + t*64 + g*4);     // broadcast
        acc[t] = fmaf(w.x, a.x, fmaf(w.y, a.y, fmaf(w.z, a.z, fmaf(w.w, a.w, acc[t]))));
      }
    }
    __syncthreads();
  }

  const float b = bias ? bias[c] : 0.f;
#pragma unroll
  for (int t = 0; t < 8; ++t) {
    const int gr = m0 + wave*8 + t;
    if (gr < M) {
      float v = acc[t] + b;
      if (RELU) v = fmaxf(v, 0.f);
      float* cp = C + (size_t)gr*ldc + c;
      if (ACC) v += *cp;
      *cp = v;
    }
  }
}

// ---------------------------------------------------------------------------
// Dynamic conv: per target i, 17 neighbors (16 kNN + self).
// t_e = relu(P[i] + Q[j]); out[i][c] = relu(max_e (t_e . W2[c]) + b2[c]).
// W2 staged f4-transposed [g][c] -> conflict-free b128; T reads broadcast.
// ---------------------------------------------------------------------------
template<int NB>
__device__ __forceinline__ float dyn_block(
    int i, int nb0, const int* __restrict__ knn,
    const float* __restrict__ PQ,
    const float* __restrict__ w2s, float* __restrict__ Tw,
    int lane, float vmax)
{
  for (int idx = lane; idx < NB * 32; idx += 64) {
    const int off = idx << 2;
    const int nb = off >> 7, kk = off & 127;
    const int nbg = nb0 + nb;
    const int j = (nbg < 16) ? knn[(size_t)i*16 + nbg] : i;
    const float4 p = *(const float4*)(PQ + (size_t)i*256 + kk);
    const float4 q = *(const float4*)(PQ + (size_t)j*256 + 128 + kk);
    float4 t;
    t.x = fmaxf(p.x + q.x, 0.f); t.y = fmaxf(p.y + q.y, 0.f);
    t.z = fmaxf(p.z + q.z, 0.f); t.w = fmaxf(p.w + q.w, 0.f);
    *(float4*)(Tw + off) = t;
  }
  __syncthreads();
  float acc[NB];
#pragma unroll
  for (int t = 0; t < NB; ++t) acc[t] = 0.f;
  for (int g = 0; g < 32; ++g) {
    const float4 w = *(const float4*)(w2s + (g*64 + lane)*4);   // conflict-free
#pragma unroll
    for (int t = 0; t < NB; ++t) {
      const float4 tv = *(const float4*)(Tw + t*128 + g*4);     // broadcast
      acc[t] = fmaf(w.x, tv.x, fmaf(w.y, tv.y, fmaf(w.z, tv.z, fmaf(w.w, tv.w, acc[t]))));
    }
  }
#pragma unroll
  for (int t = 0; t < NB; ++t) vmax = fmaxf(vmax, acc[t]);
  return vmax;
}

__global__ __launch_bounds__(256) void dyn_conv_kernel(
    const float* __restrict__ PQ,
    const float* __restrict__ W2, const float* __restrict__ b2,
    const int* __restrict__ knn, float* __restrict__ out, int ldo, int n)
{
  __shared__ float w2s[32 * 64 * 4];   // [g][c] float4 of W2 rows
  __shared__ float T[4][1152];         // per-wave [9][128]
  for (int idx = threadIdx.x; idx < 2048; idx += 256) {
    const int ch = idx & 63, g = idx >> 6;
    *(float4*)(w2s + idx*4) = *(const float4*)(W2 + (size_t)ch*128 + g*4);
  }
  __syncthreads();
  const int wave = threadIdx.x >> 6, lane = threadIdx.x & 63;
  const int i = blockIdx.x * 4 + wave;
  float vmax = -INF_F;
  vmax = dyn_block<9>(i, 0, knn, PQ, w2s, T[wave], lane, vmax);
  vmax = dyn_block<8>(i, 9, knn, PQ, w2s, T[wave], lane, vmax);
  if (i < n) out[(size_t)i*ldo + lane] = fmaxf(vmax + b2[lane], 0.f);
}

// ---------------------------------------------------------------------------
// Host orchestration
// ---------------------------------------------------------------------------
extern "C" void kernel_launch(void* const* d_in, const int* in_sizes, int n_in,
                              void* d_out, int out_size, void* d_ws, size_t ws_size,
                              hipStream_t stream)
{
  const float* x   = (const float*)d_in[0];
  const int*   ei  = (const int*)d_in[1];
  const float* ea  = (const float*)d_in[2];
  const float* loc = (const float*)d_in[3];
  const float* sg_wm[3] = {(const float*)d_in[5],  (const float*)d_in[9],  (const float*)d_in[13]};
  const float* sg_bm[3] = {(const float*)d_in[6],  (const float*)d_in[10], (const float*)d_in[14]};
  const float* sg_wu[3] = {(const float*)d_in[7],  (const float*)d_in[11], (const float*)d_in[15]};
  const float* sg_bu[3] = {(const float*)d_in[8],  (const float*)d_in[12], (const float*)d_in[16]};
  const float* dg_w1[2] = {(const float*)d_in[17], (const float*)d_in[21]};
  const float* dg_b1[2] = {(const float*)d_in[18], (const float*)d_in[22]};
  const float* dg_w2[2] = {(const float*)d_in[19], (const float*)d_in[23]};
  const float* dg_b2[2] = {(const float*)d_in[20], (const float*)d_in[24]};
  const float* f1_w = (const float*)d_in[25];
  const float* f1_b = (const float*)d_in[26];
  const float* f2_w = (const float*)d_in[27];
  const float* f2_b = (const float*)d_in[28];
  float* out = (float*)d_out;

  const int n    = in_sizes[0] / 64;
  const int Etot = in_sizes[1] / 2;
  const int* srcp = ei;
  const int* dstp = ei + Etot;

  char* basep = (char*)d_ws;
  size_t cur = 0;
  auto alloc = [&](size_t bytes) -> void* {
    void* p = basep + cur;
    cur = (cur + bytes + 255) & ~(size_t)255;
    return p;
  };
  float* CAT  = (float*)alloc((size_t)n * 320 * 4);
  float* Rb   = (float*)alloc((size_t)n * 64 * 4);
  float* PQb  = (float*)alloc((size_t)n * 256 * 4);
  float* agg  = (float*)alloc((size_t)n * 64 * 4);
  float* fu1  = (float*)alloc((size_t)n * 64 * 4);
  float* wpq[2];
  float* bpq[2];
  wpq[0] = (float*)alloc(256 * 64 * 4);  bpq[0] = (float*)alloc(256 * 4);
  wpq[1] = (float*)alloc(256 * 64 * 4);  bpq[1] = (float*)alloc(256 * 4);
  int* knnb   = (int*)alloc((size_t)n * 16 * 4);
  // zero region: [cellcount NC][cellfill NC][deg n][dfill n]
  int* zeros     = (int*)alloc((size_t)(2*KNN_NC + 2*n) * 4);
  int* cellcount = zeros;
  int* cellfill  = zeros + KNN_NC;
  int* deg       = zeros + 2*KNN_NC;
  int* dfill     = zeros + 2*KNN_NC + n;
  int* cellstart = (int*)alloc((size_t)(KNN_NC + 1) * 4);
  int* cellidb   = (int*)alloc((size_t)n * 4);
  float* locs4s  = (float*)alloc((size_t)n * 4 * 4);
  int* oidx      = (int*)alloc((size_t)n * 4);
  int* rowptr    = (int*)alloc((size_t)(n + 1) * 4);
  int* cs_src    = (int*)alloc((size_t)Etot * 4);
  int* cs_eid    = (int*)alloc((size_t)Etot * 4);
  (void)ws_size; (void)n_in; (void)out_size;

  const int nb256 = (n + 255) / 256;

  hipMemsetAsync(zeros, 0, (size_t)(2*KNN_NC + 2*n) * 4, stream);
  // kNN bin build + wave-per-target query
  bin_count_kernel<<<nb256, 256, 0, stream>>>(loc, cellcount, cellidb, n);
  scan1b_kernel<<<1, 1024, 0, stream>>>(cellcount, cellstart, KNN_NC,
                                        (KNN_NC + 1023) / 1024);
  bin_scatter_kernel<<<nb256, 256, 0, stream>>>(loc, cellidb, cellstart,
                                                cellfill, locs4s, oidx, n);
  knn_wave_kernel<<<(n + 3) / 4, 256, 0, stream>>>(locs4s, oidx, cellstart,
                                                   knnb, n);
  // static CSR build
  deg_kernel<<<(Etot + 255) / 256, 256, 0, stream>>>(dstp, deg, Etot);
  scan1b_kernel<<<1, 1024, 0, stream>>>(deg, rowptr, n, (n + 1023) / 1024);
  csr_scatter_kernel<<<(Etot + 255) / 256, 256, 0, stream>>>(
      srcp, dstp, rowptr, dfill, cs_src, cs_eid, Etot);
  // dyn weight packing
  pack_kernel<<<32, 256, 0, stream>>>(dg_w1[0], dg_b1[0], wpq[0], bpq[0]);
  pack_kernel<<<32, 256, 0, stream>>>(dg_w1[1], dg_b1[1], wpq[1], bpq[1]);

  const int mb = (n + 31) / 32;
  auto lin = [&](const float* A, int lda, const float* W, int ldw, const float* bias,
                 float* C, int ldc, int K, int ncols, bool relu, bool accum) {
    dim3 grid(mb, ncols / 64);
    if (relu)       linear_kernel<true,  false><<<grid, 256, 0, stream>>>(A, lda, W, ldw, bias, C, ldc, n, K);
    else if (accum) linear_kernel<false, true ><<<grid, 256, 0, stream>>>(A, lda, W, ldw, bias, C, ldc, n, K);
    else            linear_kernel<false, false><<<grid, 256, 0, stream>>>(A, lda, W, ldw, bias, C, ldc, n, K);
  };

  // static layers: x -> h1(CAT+0) -> h2(CAT+192) -> h3(CAT+256)
  const float* hin = x; int hlda = 64;
  float* hout[3] = {CAT + 0, CAT + 192, CAT + 256};
  for (int l = 0; l < 3; ++l) {
    lin(hin, hlda, sg_wm[l] + 16, 80, nullptr, Rb, 64, 64, 64, false, false);
    static_msg_kernel<<<(n + 3) / 4, 256, 0, stream>>>(Rb, ea, sg_wm[l], sg_bm[l],
                                                       cs_src, cs_eid, rowptr, agg, n);
    lin(agg, 64, sg_wu[l], 64, sg_bu[l], hout[l], 320, 64, 64, true, false);
    hin = hout[l]; hlda = 320;
  }

  // dynamic layers: h1 -> g1(CAT+64); g1 -> g2(CAT+128)
  const float* din[2] = {CAT + 0, CAT + 64};
  float* doutp[2] = {CAT + 64, CAT + 128};
  for (int l = 0; l < 2; ++l) {
    lin(din[l], 320, wpq[l], 64, bpq[l], PQb, 256, 64, 256, false, false);
    dyn_conv_kernel<<<(n + 3) / 4, 256, 0, stream>>>(PQb, dg_w2[l], dg_b2[l],
                                                     knnb, doutp[l], 320, n);
  }

  // fusion
  lin(CAT, 320, f1_w, 320, f1_b, fu1, 64, 320, 64, true,  false);
  lin(CAT, 320, f2_w + 64, 384, f2_b, out, 64, 320, 64, false, false);
  lin(fu1, 64, f2_w, 384, nullptr, out, 64, 64, 64, false, true);
}

// Round 6
// 558.113 us; speedup vs baseline: 2.6525x; 1.1535x over previous
//
#include <hip/hip_runtime.h>

#define INF_F __builtin_inff()

typedef __attribute__((ext_vector_type(8))) short short8v;  // 8 bf16
typedef __attribute__((ext_vector_type(4))) float f32x4;

__device__ __forceinline__ short f2bf(float x) {
  const unsigned u = __float_as_uint(x);
  return (short)((u + 0x7FFFu + ((u >> 16) & 1u)) >> 16);   // RNE
}

// ===========================================================================
// Spatial-bin exact kNN, WAVE-per-target (unchanged from round 5).
// ===========================================================================
#define KNN_G 4
#define KNN_NC (KNN_G*KNN_G*KNN_G*KNN_G)   // 256

__global__ __launch_bounds__(256) void bin_count_kernel(
    const float* __restrict__ loc, int* __restrict__ cellcount,
    int* __restrict__ cellid, int n)
{
  const int i = blockIdx.x * 256 + threadIdx.x;
  if (i >= n) return;
  const float4 l = *(const float4*)(loc + (size_t)i*4);
  const int cx = min(KNN_G-1, (int)(l.x * (float)KNN_G));
  const int cy = min(KNN_G-1, (int)(l.y * (float)KNN_G));
  const int cz = min(KNN_G-1, (int)(l.z * (float)KNN_G));
  const int cw = min(KNN_G-1, (int)(l.w * (float)KNN_G));
  const int c = ((cx*KNN_G + cy)*KNN_G + cz)*KNN_G + cw;
  cellid[i] = c;
  atomicAdd(&cellcount[c], 1);
}

__global__ __launch_bounds__(256) void bin_scatter_kernel(
    const float* __restrict__ loc, const int* __restrict__ cellid,
    const int* __restrict__ cellstart, int* __restrict__ cellfill,
    float* __restrict__ locs4s, int* __restrict__ oidx, int n)
{
  const int i = blockIdx.x * 256 + threadIdx.x;
  if (i >= n) return;
  const int c = cellid[i];
  const int pos = cellstart[c] + atomicAdd(&cellfill[c], 1);
  *(float4*)(locs4s + (size_t)pos*4) = *(const float4*)(loc + (size_t)i*4);
  oidx[pos] = i;
}

__device__ __forceinline__ unsigned long long
knn_refine16(unsigned long long* __restrict__ B, int cnt, int lane,
             unsigned long long& topsave)
{
  unsigned long long v[5];
#pragma unroll
  for (int s = 0; s < 5; ++s) {
    const int idx = lane + 64*s;
    v[s] = (idx < cnt) ? B[idx] : ~0ull;
  }
  unsigned long long tau = ~0ull;
#pragma unroll
  for (int r = 0; r < 16; ++r) {
    unsigned long long m = v[0]; int sl = 0;
#pragma unroll
    for (int s = 1; s < 5; ++s) if (v[s] < m) { m = v[s]; sl = s; }
    unsigned long long mm = m;
#pragma unroll
    for (int off = 32; off >= 1; off >>= 1) {
      const unsigned long long o = __shfl_xor(mm, off, 64);
      if (o < mm) mm = o;
    }
    const bool killer = (m == mm);
#pragma unroll
    for (int s = 0; s < 5; ++s) if (killer && sl == s) v[s] = ~0ull;
    if (lane == r) topsave = mm;
    tau = mm;
  }
  if (lane < 16) B[lane] = topsave;
  return tau;
}

__global__ __launch_bounds__(256) void knn_wave_kernel(
    const float* __restrict__ locs4s, const int* __restrict__ oidx,
    const int* __restrict__ cellstart, int* __restrict__ knn, int n)
{
#pragma clang fp contract(off)
  constexpr int CAP = 320, TRIG = 256;
  __shared__ unsigned long long Bs[4][CAP];
  const int wave = threadIdx.x >> 6, lane = threadIdx.x & 63;
  const int t = blockIdx.x * 4 + wave;
  if (t >= n) return;
  unsigned long long* B = Bs[wave];

  const float4 L = *(const float4*)(locs4s + (size_t)t*4);
  const float tx = L.x, ty = L.y, tz = L.z, tw = L.w;
  const int cx = min(KNN_G-1, (int)(tx * (float)KNN_G));
  const int cy = min(KNN_G-1, (int)(ty * (float)KNN_G));
  const int cz = min(KNN_G-1, (int)(tz * (float)KNN_G));
  const int cw = min(KNN_G-1, (int)(tw * (float)KNN_G));

  unsigned long long tau = ~0ull;
  unsigned long long topsave = ~0ull;
  int cnt = 0;

  auto do_range = [&](int ps, int pe) {
    for (int p0 = ps; p0 < pe; p0 += 64) {
      const int p = p0 + lane;
      unsigned long long key = ~0ull;
      if (p < pe && p != t) {
        const float4 q = *(const float4*)(locs4s + (size_t)p*4);
        const int oj = oidx[p];
        const float a0 = q.x - tx, a1 = q.y - ty, a2 = q.z - tz, a3 = q.w - tw;
        const float s0 = a0*a0, s1 = a1*a1, s2 = a2*a2, s3 = a3*a3;
        const float d = ((s0 + s1) + s2) + s3;
        key = ((unsigned long long)__float_as_uint(d) << 32) | (unsigned)oj;
      }
      const bool surv = key < tau;
      const unsigned long long mask = __ballot(surv);
      if (mask) {
        const unsigned pre = __builtin_amdgcn_mbcnt_hi(
            (unsigned)(mask >> 32),
            __builtin_amdgcn_mbcnt_lo((unsigned)mask, 0u));
        if (surv) B[cnt + pre] = key;
        cnt += (int)__popcll(mask);
        if (cnt > TRIG) { tau = knn_refine16(B, cnt, lane, topsave); cnt = 16; }
      }
    }
  };

  // level 0: radius-1 block; lane r<27 prefetches combo r's range
  int psv = 0, pev = 0;
  if (lane < 27) {
    const int ax = cx + (lane / 9) - 1;
    const int ay = cy + ((lane / 3) % 3) - 1;
    const int az = cz + (lane % 3) - 1;
    if (ax >= 0 && ax < KNN_G && ay >= 0 && ay < KNN_G &&
        az >= 0 && az < KNN_G) {
      const int base = ((ax*KNN_G + ay)*KNN_G + az)*KNN_G;
      const int wlo = max(cw-1, 0), whi = min(cw+1, KNN_G-1);
      psv = cellstart[base + wlo];
      pev = cellstart[base + whi + 1];
    }
  }
  for (int r = 0; r < 27; ++r) {
    const int ps = __shfl(psv, r, 64);
    const int pe = __shfl(pev, r, 64);
    if (ps < pe) do_range(ps, pe);
  }

  // shells m = 2..G-1 (rare)
  for (int m = 2; m <= KNN_G - 1; ++m) {
    if (cnt > 16) { tau = knn_refine16(B, cnt, lane, topsave); cnt = 16; }
    if (tau != ~0ull) {
      const float taud = __uint_as_float((unsigned)(tau >> 32));
      const float r = (float)(m - 1) * (1.0f / (float)KNN_G);
      if (taud < r * r * 0.99999f) break;
    }
    const int xlo = max(cx-m, 0), xhi = min(cx+m, KNN_G-1);
    for (int ax = xlo; ax <= xhi; ++ax) {
      const bool xe = (ax == cx-m) || (ax == cx+m);
      const int ylo = max(cy-m, 0), yhi = min(cy+m, KNN_G-1);
      for (int ay = ylo; ay <= yhi; ++ay) {
        const bool ye = (ay == cy-m) || (ay == cy+m);
        const int zlo = max(cz-m, 0), zhi = min(cz+m, KNN_G-1);
        for (int az = zlo; az <= zhi; ++az) {
          const bool ze = (az == cz-m) || (az == cz+m);
          const int base = ((ax*KNN_G + ay)*KNN_G + az)*KNN_G;
          if (xe | ye | ze) {
            const int wlo = max(cw-m, 0), whi = min(cw+m, KNN_G-1);
            do_range(cellstart[base+wlo], cellstart[base+whi+1]);
          } else {
            if (cw-m >= 0) {
              const int c = base + cw - m;
              do_range(cellstart[c], cellstart[c+1]);
            }
            if (cw+m <= KNN_G-1) {
              const int c = base + cw + m;
              do_range(cellstart[c], cellstart[c+1]);
            }
          }
        }
      }
    }
  }
  if (cnt > 16) (void)knn_refine16(B, cnt, lane, topsave);
  const int i = oidx[t];
  if (lane < 16) knn[(size_t)i*16 + lane] = (int)(topsave & 0xFFFFFFFFull);
}

// ---------------------------------------------------------------------------
// Single-block exclusive scan
// ---------------------------------------------------------------------------
__global__ __launch_bounds__(1024) void scan1b_kernel(
    const int* __restrict__ in, int* __restrict__ out, int n, int per)
{
  __shared__ int part[1024];
  const int t = threadIdx.x;
  const int lo = t * per, hi = min(lo + per, n);
  int sum = 0;
  for (int idx = lo; idx < hi; ++idx) sum += in[idx];
  int v = sum;
  part[t] = v;
  __syncthreads();
  for (int off = 1; off < 1024; off <<= 1) {
    const int o = (t >= off) ? part[t - off] : 0;
    __syncthreads();
    v += o;
    part[t] = v;
    __syncthreads();
  }
  int run = v - sum;
  for (int idx = lo; idx < hi; ++idx) { out[idx] = run; run += in[idx]; }
  if (t == 1023) out[n] = v;
}

// ---------------------------------------------------------------------------
// Static-graph CSR build (dst-grouped)
// ---------------------------------------------------------------------------
__global__ __launch_bounds__(256) void deg_kernel(const int* __restrict__ dst,
                                                  int* __restrict__ deg, int E)
{
  const int e = blockIdx.x * 256 + threadIdx.x;
  if (e < E) atomicAdd(&deg[dst[e]], 1);
}

__global__ __launch_bounds__(256) void csr_scatter_kernel(
    const int* __restrict__ srcs, const int* __restrict__ dsts,
    const int* __restrict__ rowptr, int* __restrict__ dfill,
    int* __restrict__ cs_src, int* __restrict__ cs_eid, int E)
{
  const int e = blockIdx.x * 256 + threadIdx.x;
  if (e < E) {
    const int d = dsts[e];
    const int pos = rowptr[d] + atomicAdd(&dfill[d], 1);
    cs_src[pos] = srcs[e];
    cs_eid[pos] = e;
  }
}

// ---------------------------------------------------------------------------
// Static conv message + segment max, 2-wide software pipeline.
// ---------------------------------------------------------------------------
__global__ __launch_bounds__(256) void static_msg_kernel(
    const float* __restrict__ R, const float* __restrict__ ea,
    const float* __restrict__ wm, const float* __restrict__ bm,
    const int* __restrict__ cs_src, const int* __restrict__ cs_eid,
    const int* __restrict__ rowptr, float* __restrict__ agg, int n)
{
  __shared__ float wma[64][17];
  for (int idx = threadIdx.x; idx < 1024; idx += 256) {
    const int r = idx >> 4, cc = idx & 15;
    wma[r][cc] = wm[r*80 + cc];
  }
  __syncthreads();
  const int wave = threadIdx.x >> 6, lane = threadIdx.x & 63;
  const int d = blockIdx.x * 4 + wave;
  if (d >= n) return;
  const int beg = rowptr[d], end = rowptr[d+1];
  const float base = bm[lane] - R[(size_t)d*64 + lane];
  const float* wr = wma[lane];
  float vmax = 0.f;
  int p = beg;
  for (; p + 2 <= end; p += 2) {
    const int s0 = cs_src[p],   e0 = cs_eid[p];
    const int s1 = cs_src[p+1], e1 = cs_eid[p+1];
    const float r0 = R[(size_t)s0*64 + lane];
    const float r1 = R[(size_t)s1*64 + lane];
    const float4* A4 = (const float4*)(ea + (size_t)e0*16);
    const float4* B4 = (const float4*)(ea + (size_t)e1*16);
    const float4 a0 = A4[0], a1 = A4[1], a2 = A4[2], a3 = A4[3];
    const float4 c0 = B4[0], c1 = B4[1], c2 = B4[2], c3 = B4[3];
    float x = base + r0, y = base + r1;
    x = fmaf(a0.x, wr[0],  x); y = fmaf(c0.x, wr[0],  y);
    x = fmaf(a0.y, wr[1],  x); y = fmaf(c0.y, wr[1],  y);
    x = fmaf(a0.z, wr[2],  x); y = fmaf(c0.z, wr[2],  y);
    x = fmaf(a0.w, wr[3],  x); y = fmaf(c0.w, wr[3],  y);
    x = fmaf(a1.x, wr[4],  x); y = fmaf(c1.x, wr[4],  y);
    x = fmaf(a1.y, wr[5],  x); y = fmaf(c1.y, wr[5],  y);
    x = fmaf(a1.z, wr[6],  x); y = fmaf(c1.z, wr[6],  y);
    x = fmaf(a1.w, wr[7],  x); y = fmaf(c1.w, wr[7],  y);
    x = fmaf(a2.x, wr[8],  x); y = fmaf(c2.x, wr[8],  y);
    x = fmaf(a2.y, wr[9],  x); y = fmaf(c2.y, wr[9],  y);
    x = fmaf(a2.z, wr[10], x); y = fmaf(c2.z, wr[10], y);
    x = fmaf(a2.w, wr[11], x); y = fmaf(c2.w, wr[11], y);
    x = fmaf(a3.x, wr[12], x); y = fmaf(c3.x, wr[12], y);
    x = fmaf(a3.y, wr[13], x); y = fmaf(c3.y, wr[13], y);
    x = fmaf(a3.z, wr[14], x); y = fmaf(c3.z, wr[14], y);
    x = fmaf(a3.w, wr[15], x); y = fmaf(c3.w, wr[15], y);
    vmax = fmaxf(vmax, fmaxf(x, y));
  }
  if (p < end) {
    const int s0 = cs_src[p], e0 = cs_eid[p];
    float x = base + R[(size_t)s0*64 + lane];
    const float4* A4 = (const float4*)(ea + (size_t)e0*16);
    const float4 a0 = A4[0], a1 = A4[1], a2 = A4[2], a3 = A4[3];
    x = fmaf(a0.x, wr[0],  x); x = fmaf(a0.y, wr[1],  x);
    x = fmaf(a0.z, wr[2],  x); x = fmaf(a0.w, wr[3],  x);
    x = fmaf(a1.x, wr[4],  x); x = fmaf(a1.y, wr[5],  x);
    x = fmaf(a1.z, wr[6],  x); x = fmaf(a1.w, wr[7],  x);
    x = fmaf(a2.x, wr[8],  x); x = fmaf(a2.y, wr[9],  x);
    x = fmaf(a2.z, wr[10], x); x = fmaf(a2.w, wr[11], x);
    x = fmaf(a3.x, wr[12], x); x = fmaf(a3.y, wr[13], x);
    x = fmaf(a3.z, wr[14], x); x = fmaf(a3.w, wr[15], x);
    vmax = fmaxf(vmax, x);
  }
  agg[(size_t)d*64 + lane] = vmax;
}

// ---------------------------------------------------------------------------
// Pack dyn-layer weights: Wpq[256][64] = [w1a - w1b ; w1b], bpq = [b1 ; 0].
// ---------------------------------------------------------------------------
__global__ __launch_bounds__(256) void pack_kernel(const float* __restrict__ w1,
                                                   const float* __restrict__ b1,
                                                   float* __restrict__ wpq,
                                                   float* __restrict__ bpq)
{
  const int idx = blockIdx.x * 256 + threadIdx.x;
  if (idx < 128 * 64) {
    const int o = idx >> 6, i = idx & 63;
    const float a = w1[o*128 + i], b = w1[o*128 + 64 + i];
    wpq[idx] = a - b;
    wpq[128*64 + idx] = b;
  }
  if (idx < 128) { bpq[idx] = b1[idx]; bpq[128 + idx] = 0.f; }
}

// ---------------------------------------------------------------------------
// Generic fp32 linear (unchanged)
// ---------------------------------------------------------------------------
template<bool RELU, bool ACC>
__global__ __launch_bounds__(256) void linear_kernel(
    const float* __restrict__ A, int lda,
    const float* __restrict__ W, int ldw,
    const float* __restrict__ bias,
    float* __restrict__ C, int ldc, int M, int K)
{
  __shared__ float As[32 * 64];
  __shared__ float Ws[16 * 64 * 4];
  const int m0 = blockIdx.x * 32;
  const int c0 = blockIdx.y * 64;
  const int tid = threadIdx.x;
  const int wave = tid >> 6, lane = tid & 63;
  const int c = c0 + lane;

  float acc[8];
#pragma unroll
  for (int t = 0; t < 8; ++t) acc[t] = 0.f;

  for (int kt = 0; kt < K; kt += 64) {
    {
      int idx = tid;
#pragma unroll
      for (int itr = 0; itr < 2; ++itr, idx += 256) {
        const int row = idx >> 4, col4 = idx & 15;
        const int gr = m0 + row;
        float4 v = make_float4(0.f, 0.f, 0.f, 0.f);
        if (gr < M) v = *(const float4*)(A + (size_t)gr*lda + kt + col4*4);
        *(float4*)(As + row*64 + col4*4) = v;
      }
      idx = tid;
#pragma unroll
      for (int itr = 0; itr < 4; ++itr, idx += 256) {
        const int ch = idx & 63, g = idx >> 6;
        const float4 v = *(const float4*)(W + (size_t)(c0 + ch)*ldw + kt + g*4);
        *(float4*)(Ws + idx*4) = v;
      }
    }
    __syncthreads();
    const float* ar = As + wave*8*64;
    for (int g = 0; g < 16; ++g) {
      const float4 w = *(const float4*)(Ws + (g*64 + lane)*4);
#pragma unroll
      for (int t = 0; t < 8; ++t) {
        const float4 a = *(const float4*)(ar + t*64 + g*4);
        acc[t] = fmaf(w.x, a.x, fmaf(w.y, a.y, fmaf(w.z, a.z, fmaf(w.w, a.w, acc[t]))));
      }
    }
    __syncthreads();
  }

  const float b = bias ? bias[c] : 0.f;
#pragma unroll
  for (int t = 0; t < 8; ++t) {
    const int gr = m0 + wave*8 + t;
    if (gr < M) {
      float v = acc[t] + b;
      if (RELU) v = fmaxf(v, 0.f);
      float* cp = C + (size_t)gr*ldc + c;
      if (ACC) v += *cp;
      *cp = v;
    }
  }
}

// ---------------------------------------------------------------------------
// Dynamic conv via MFMA (bf16). One wave : 4 targets, 4 waves/block.
// Per target: T[17][128] bf16 in LDS (16 kNN rows + self row 16);
// D = T @ W2^T as mfma_f32_16x16x32_bf16: M-tile0 = kNN rows, M-tile1 = self
// row broadcast (dup rows, max-safe); B (w2) preloaded once into 16 frags.
// out[i][c] = relu(max_rows(D) + b2[c]).  relu∘max commute.
// LDS pitch 136 bf16 (272 B) -> conflict-free-ish b128 frag reads.
// ---------------------------------------------------------------------------
#define TPW 4   // targets per wave

__global__ __launch_bounds__(256) void dyn_mfma_kernel(
    const float* __restrict__ PQ,
    const float* __restrict__ W2, const float* __restrict__ b2,
    const int* __restrict__ knn, float* __restrict__ out, int ldo, int n)
{
  __shared__ short w2s[64 * 136];      // bf16 [c][k], pitch 136
  __shared__ short Ts[4][17 * 136];    // per-wave T, pitch 136
  const int tid = threadIdx.x;
  const int wave = tid >> 6, lane = tid & 63;

  // stage w2 -> bf16 LDS
  for (int idx = tid; idx < 64 * 128; idx += 256) {
    const int c = idx >> 7, k = idx & 127;
    w2s[c*136 + k] = f2bf(W2[c*128 + k]);
  }
  __syncthreads();

  // preload B fragments: bfr[nt][kt], col = lane&15, k = kt*32+(lane>>4)*8
  short8v bfr[4][4];
#pragma unroll
  for (int nt = 0; nt < 4; ++nt)
#pragma unroll
    for (int kt = 0; kt < 4; ++kt)
      bfr[nt][kt] = *(const short8v*)&w2s[(nt*16 + (lane&15))*136 +
                                          kt*32 + (lane>>4)*8];
  const float b2v = b2[lane];
  short* T = Ts[wave];

  for (int tg = 0; tg < TPW; ++tg) {
    const int i = (blockIdx.x * 4 + wave) * TPW + tg;
    if (i >= n) break;
    const size_t i16 = (size_t)i * 16;

    // build T: 17 rows x 32 float4-slots = 544 slots
    for (int s = 0; s < 9; ++s) {
      const int slot = lane + 64*s;
      if (slot < 544) {
        const int row = slot >> 5, k4 = slot & 31;
        const int j = (row < 16) ? knn[i16 + row] : i;
        const float4 p = *(const float4*)(PQ + (size_t)i*256 + k4*4);
        const float4 q = *(const float4*)(PQ + (size_t)j*256 + 128 + k4*4);
        const float t0 = fmaxf(p.x + q.x, 0.f), t1 = fmaxf(p.y + q.y, 0.f);
        const float t2 = fmaxf(p.z + q.z, 0.f), t3 = fmaxf(p.w + q.w, 0.f);
        int2 w;
        w.x = ((int)(unsigned short)f2bf(t1) << 16) | (unsigned short)f2bf(t0);
        w.y = ((int)(unsigned short)f2bf(t3) << 16) | (unsigned short)f2bf(t2);
        *(int2*)&T[row*136 + k4*4] = w;
      }
    }
    // same-wave ds_write -> ds_read ordering handled by compiler lgkmcnt

    f32x4 acc0[4], acc1[4];
#pragma unroll
    for (int nt = 0; nt < 4; ++nt) {
      acc0[nt] = (f32x4)0.f;
      acc1[nt] = (f32x4)0.f;
    }
#pragma unroll
    for (int kt = 0; kt < 4; ++kt) {
      const short8v a1 = *(const short8v*)&T[(lane&15)*136 + kt*32 + (lane>>4)*8];
      const short8v a2 = *(const short8v*)&T[16*136 + kt*32 + (lane>>4)*8];
#pragma unroll
      for (int nt = 0; nt < 4; ++nt) {
        acc0[nt] = __builtin_amdgcn_mfma_f32_16x16x32_bf16(a1, bfr[nt][kt], acc0[nt], 0, 0, 0);
        acc1[nt] = __builtin_amdgcn_mfma_f32_16x16x32_bf16(a2, bfr[nt][kt], acc1[nt], 0, 0, 0);
      }
    }

    // epilogue: col = lane&15, rows (lane>>4)*4+j ; max over rows then lanes
    float v[4];
#pragma unroll
    for (int nt = 0; nt < 4; ++nt) {
      float m = fmaxf(fmaxf(acc0[nt][0], acc0[nt][1]),
                      fmaxf(acc0[nt][2], acc0[nt][3]));
      m = fmaxf(m, acc1[nt][0]);                 // self (dup rows)
      m = fmaxf(m, __shfl_xor(m, 16, 64));
      m = fmaxf(m, __shfl_xor(m, 32, 64));
      v[nt] = m;
    }
    const int g = lane >> 4;
    float r = v[0];
    r = (g == 1) ? v[1] : r;
    r = (g == 2) ? v[2] : r;
    r = (g == 3) ? v[3] : r;
    out[(size_t)i*ldo + lane] = fmaxf(r + b2v, 0.f);
  }
}

// ---------------------------------------------------------------------------
// Host orchestration
// ---------------------------------------------------------------------------
extern "C" void kernel_launch(void* const* d_in, const int* in_sizes, int n_in,
                              void* d_out, int out_size, void* d_ws, size_t ws_size,
                              hipStream_t stream)
{
  const float* x   = (const float*)d_in[0];
  const int*   ei  = (const int*)d_in[1];
  const float* ea  = (const float*)d_in[2];
  const float* loc = (const float*)d_in[3];
  const float* sg_wm[3] = {(const float*)d_in[5],  (const float*)d_in[9],  (const float*)d_in[13]};
  const float* sg_bm[3] = {(const float*)d_in[6],  (const float*)d_in[10], (const float*)d_in[14]};
  const float* sg_wu[3] = {(const float*)d_in[7],  (const float*)d_in[11], (const float*)d_in[15]};
  const float* sg_bu[3] = {(const float*)d_in[8],  (const float*)d_in[12], (const float*)d_in[16]};
  const float* dg_w1[2] = {(const float*)d_in[17], (const float*)d_in[21]};
  const float* dg_b1[2] = {(const float*)d_in[18], (const float*)d_in[22]};
  const float* dg_w2[2] = {(const float*)d_in[19], (const float*)d_in[23]};
  const float* dg_b2[2] = {(const float*)d_in[20], (const float*)d_in[24]};
  const float* f1_w = (const float*)d_in[25];
  const float* f1_b = (const float*)d_in[26];
  const float* f2_w = (const float*)d_in[27];
  const float* f2_b = (const float*)d_in[28];
  float* out = (float*)d_out;

  const int n    = in_sizes[0] / 64;
  const int Etot = in_sizes[1] / 2;
  const int* srcp = ei;
  const int* dstp = ei + Etot;

  char* basep = (char*)d_ws;
  size_t cur = 0;
  auto alloc = [&](size_t bytes) -> void* {
    void* p = basep + cur;
    cur = (cur + bytes + 255) & ~(size_t)255;
    return p;
  };
  float* CAT  = (float*)alloc((size_t)n * 320 * 4);
  float* Rb   = (float*)alloc((size_t)n * 64 * 4);
  float* PQb  = (float*)alloc((size_t)n * 256 * 4);
  float* agg  = (float*)alloc((size_t)n * 64 * 4);
  float* fu1  = (float*)alloc((size_t)n * 64 * 4);
  float* wpq[2];
  float* bpq[2];
  wpq[0] = (float*)alloc(256 * 64 * 4);  bpq[0] = (float*)alloc(256 * 4);
  wpq[1] = (float*)alloc(256 * 64 * 4);  bpq[1] = (float*)alloc(256 * 4);
  int* knnb   = (int*)alloc((size_t)n * 16 * 4);
  int* zeros     = (int*)alloc((size_t)(2*KNN_NC + 2*n) * 4);
  int* cellcount = zeros;
  int* cellfill  = zeros + KNN_NC;
  int* deg       = zeros + 2*KNN_NC;
  int* dfill     = zeros + 2*KNN_NC + n;
  int* cellstart = (int*)alloc((size_t)(KNN_NC + 1) * 4);
  int* cellidb   = (int*)alloc((size_t)n * 4);
  float* locs4s  = (float*)alloc((size_t)n * 4 * 4);
  int* oidx      = (int*)alloc((size_t)n * 4);
  int* rowptr    = (int*)alloc((size_t)(n + 1) * 4);
  int* cs_src    = (int*)alloc((size_t)Etot * 4);
  int* cs_eid    = (int*)alloc((size_t)Etot * 4);
  (void)ws_size; (void)n_in; (void)out_size;

  const int nb256 = (n + 255) / 256;

  hipMemsetAsync(zeros, 0, (size_t)(2*KNN_NC + 2*n) * 4, stream);
  bin_count_kernel<<<nb256, 256, 0, stream>>>(loc, cellcount, cellidb, n);
  scan1b_kernel<<<1, 1024, 0, stream>>>(cellcount, cellstart, KNN_NC,
                                        (KNN_NC + 1023) / 1024);
  bin_scatter_kernel<<<nb256, 256, 0, stream>>>(loc, cellidb, cellstart,
                                                cellfill, locs4s, oidx, n);
  knn_wave_kernel<<<(n + 3) / 4, 256, 0, stream>>>(locs4s, oidx, cellstart,
                                                   knnb, n);
  deg_kernel<<<(Etot + 255) / 256, 256, 0, stream>>>(dstp, deg, Etot);
  scan1b_kernel<<<1, 1024, 0, stream>>>(deg, rowptr, n, (n + 1023) / 1024);
  csr_scatter_kernel<<<(Etot + 255) / 256, 256, 0, stream>>>(
      srcp, dstp, rowptr, dfill, cs_src, cs_eid, Etot);
  pack_kernel<<<32, 256, 0, stream>>>(dg_w1[0], dg_b1[0], wpq[0], bpq[0]);
  pack_kernel<<<32, 256, 0, stream>>>(dg_w1[1], dg_b1[1], wpq[1], bpq[1]);

  const int mb = (n + 31) / 32;
  auto lin = [&](const float* A, int lda, const float* W, int ldw, const float* bias,
                 float* C, int ldc, int K, int ncols, bool relu, bool accum) {
    dim3 grid(mb, ncols / 64);
    if (relu)       linear_kernel<true,  false><<<grid, 256, 0, stream>>>(A, lda, W, ldw, bias, C, ldc, n, K);
    else if (accum) linear_kernel<false, true ><<<grid, 256, 0, stream>>>(A, lda, W, ldw, bias, C, ldc, n, K);
    else            linear_kernel<false, false><<<grid, 256, 0, stream>>>(A, lda, W, ldw, bias, C, ldc, n, K);
  };

  // static layers: x -> h1(CAT+0) -> h2(CAT+192) -> h3(CAT+256)
  const float* hin = x; int hlda = 64;
  float* hout[3] = {CAT + 0, CAT + 192, CAT + 256};
  for (int l = 0; l < 3; ++l) {
    lin(hin, hlda, sg_wm[l] + 16, 80, nullptr, Rb, 64, 64, 64, false, false);
    static_msg_kernel<<<(n + 3) / 4, 256, 0, stream>>>(Rb, ea, sg_wm[l], sg_bm[l],
                                                       cs_src, cs_eid, rowptr, agg, n);
    lin(agg, 64, sg_wu[l], 64, sg_bu[l], hout[l], 320, 64, 64, true, false);
    hin = hout[l]; hlda = 320;
  }

  // dynamic layers: h1 -> g1(CAT+64); g1 -> g2(CAT+128)
  const float* din[2] = {CAT + 0, CAT + 64};
  float* doutp[2] = {CAT + 64, CAT + 128};
  const int db = (n + 4*TPW - 1) / (4*TPW);
  for (int l = 0; l < 2; ++l) {
    lin(din[l], 320, wpq[l], 64, bpq[l], PQb, 256, 64, 256, false, false);
    dyn_mfma_kernel<<<db, 256, 0, stream>>>(PQb, dg_w2[l], dg_b2[l],
                                            knnb, doutp[l], 320, n);
  }

  // fusion
  lin(CAT, 320, f1_w, 320, f1_b, fu1, 64, 320, 64, true,  false);
  lin(CAT, 320, f2_w + 64, 384, f2_b, out, 64, 320, 64, false, false);
  lin(fu1, 64, f2_w, 384, nullptr, out, 64, 64, 64, false, true);
}

// Round 7
// 496.108 us; speedup vs baseline: 2.9840x; 1.1250x over previous
//
#include <hip/hip_runtime.h>

#define INF_F __builtin_inff()

typedef __attribute__((ext_vector_type(8))) short short8v;  // 8 bf16
typedef __attribute__((ext_vector_type(4))) float f32x4;
typedef unsigned long long ull;

__device__ __forceinline__ short f2bf(float x) {
  const unsigned u = __float_as_uint(x);
  return (short)((u + 0x7FFFu + ((u >> 16) & 1u)) >> 16);   // RNE
}

__device__ __forceinline__ unsigned mbcnt64(ull m) {
  return __builtin_amdgcn_mbcnt_hi((unsigned)(m >> 32),
                                   __builtin_amdgcn_mbcnt_lo((unsigned)m, 0u));
}

// ===========================================================================
// Spatial-bin exact kNN, WAVE-per-target, G=5.
// Key = (dist_bits<<32)|orig_j : u64 ascending == (dist, index) lexicographic
// == reference top_k order (dist >= 0, orig indices unique -> keys unique).
// Mid-scan pruning uses a CHEAP VALID threshold: tau' = max of 16 group
// minima (16 distinct keys) >= exact 16th-smallest, so discarding key > tau'
// can never drop a true top-16 member. Exact top-16 extracted once at end.
// Distance arithmetic matches the reference bit-for-bit: contract off,
// separately rounded squares, sequential sum.
// ===========================================================================
#define KNN_G 5
#define KNN_NC (KNN_G*KNN_G*KNN_G*KNN_G)   // 625

// ---- merged init kernels ---------------------------------------------------
__global__ __launch_bounds__(256) void count2_kernel(
    const float* __restrict__ loc, int* __restrict__ cellcount,
    int* __restrict__ cellid, int n,
    const int* __restrict__ dst, int* __restrict__ deg, int E)
{
  const int i = blockIdx.x * 256 + threadIdx.x;
  if (i < n) {
    const float4 l = *(const float4*)(loc + (size_t)i*4);
    const int cx = min(KNN_G-1, (int)(l.x * (float)KNN_G));
    const int cy = min(KNN_G-1, (int)(l.y * (float)KNN_G));
    const int cz = min(KNN_G-1, (int)(l.z * (float)KNN_G));
    const int cw = min(KNN_G-1, (int)(l.w * (float)KNN_G));
    const int c = ((cx*KNN_G + cy)*KNN_G + cz)*KNN_G + cw;
    cellid[i] = c;
    atomicAdd(&cellcount[c], 1);
  }
  if (i < E) atomicAdd(&deg[dst[i]], 1);
}

__device__ __forceinline__ void scan1b_body(
    const int* __restrict__ in, int* __restrict__ out, int n, int per)
{
  __shared__ int part[1024];
  const int t = threadIdx.x;
  const int lo = t * per, hi = min(lo + per, n);
  int sum = 0;
  for (int idx = lo; idx < hi; ++idx) sum += in[idx];
  int v = sum;
  part[t] = v;
  __syncthreads();
  for (int off = 1; off < 1024; off <<= 1) {
    const int o = (t >= off) ? part[t - off] : 0;
    __syncthreads();
    v += o;
    part[t] = v;
    __syncthreads();
  }
  int run = v - sum;
  for (int idx = lo; idx < hi; ++idx) { out[idx] = run; run += in[idx]; }
  if (t == 1023) out[n] = v;
}

__global__ __launch_bounds__(1024) void scan2_kernel(
    const int* __restrict__ inA, int* __restrict__ outA, int nA, int perA,
    const int* __restrict__ inB, int* __restrict__ outB, int nB, int perB)
{
  if (blockIdx.x == 0) scan1b_body(inA, outA, nA, perA);
  else                 scan1b_body(inB, outB, nB, perB);
}

__global__ __launch_bounds__(256) void scatter2_kernel(
    const float* __restrict__ loc, const int* __restrict__ cellid,
    const int* __restrict__ cellstart, int* __restrict__ cellfill,
    float* __restrict__ locs4s, int* __restrict__ oidx, int n,
    const int* __restrict__ srcs, const int* __restrict__ dsts,
    const int* __restrict__ rowptr, int* __restrict__ dfill,
    int* __restrict__ cs_src, int* __restrict__ cs_eid, int E)
{
  const int i = blockIdx.x * 256 + threadIdx.x;
  if (i < n) {
    const int c = cellid[i];
    const int pos = cellstart[c] + atomicAdd(&cellfill[c], 1);
    *(float4*)(locs4s + (size_t)pos*4) = *(const float4*)(loc + (size_t)i*4);
    oidx[pos] = i;
  }
  if (i < E) {
    const int d = dsts[i];
    const int pos = rowptr[d] + atomicAdd(&dfill[d], 1);
    cs_src[pos] = srcs[i];
    cs_eid[pos] = i;
  }
}

// permute edge_attr into CSR order (coalesced writes; 3 layers then stream it)
__global__ __launch_bounds__(256) void ea_perm_kernel(
    const float* __restrict__ ea, const int* __restrict__ cs_eid,
    float* __restrict__ eac, int E)
{
  const int idx = blockIdx.x * 256 + threadIdx.x;
  if (idx < E * 4) {
    const int p = idx >> 2, c = idx & 3;
    *(float4*)(eac + (size_t)p*16 + c*4) =
        *(const float4*)(ea + (size_t)cs_eid[p]*16 + c*4);
  }
}

// ---- kNN selection helpers -------------------------------------------------
__device__ __forceinline__ ull
knn_refine16(ull* __restrict__ B, int cnt, int lane, ull& topsave)
{
  ull v[5];
#pragma unroll
  for (int s = 0; s < 5; ++s) {
    const int idx = lane + 64*s;
    v[s] = (idx < cnt) ? B[idx] : ~0ull;
  }
  ull tau = ~0ull;
#pragma unroll
  for (int r = 0; r < 16; ++r) {
    ull m = v[0]; int sl = 0;
#pragma unroll
    for (int s = 1; s < 5; ++s) if (v[s] < m) { m = v[s]; sl = s; }
    ull mm = m;
#pragma unroll
    for (int off = 32; off >= 1; off >>= 1) {
      const ull o = __shfl_xor(mm, off, 64);
      if (o < mm) mm = o;
    }
    const bool killer = (m == mm);
#pragma unroll
    for (int s = 0; s < 5; ++s) if (killer && sl == s) v[s] = ~0ull;
    if (lane == r) topsave = mm;
    tau = mm;            // after round 15: exact 16th-smallest
  }
  if (lane < 16) B[lane] = topsave;
  return tau;
}

// cheap filter: tau' = max of 16 lane-quad minima (>= exact 16th-smallest);
// compact keys <= tau' to buffer front. Returns new count; sets tau.
__device__ __forceinline__ int
knn_filter(ull* __restrict__ B, int cnt, int lane, ull& tau)
{
  ull v[5];
#pragma unroll
  for (int s = 0; s < 5; ++s) {
    const int idx = lane + 64*s;
    v[s] = (idx < cnt) ? B[idx] : ~0ull;
  }
  ull g = v[0];
#pragma unroll
  for (int s = 1; s < 5; ++s) if (v[s] < g) g = v[s];
  { ull o = __shfl_xor(g, 1, 64); if (o < g) g = o;
    o = __shfl_xor(g, 2, 64); if (o < g) g = o; }
  ull t = g;
#pragma unroll
  for (int off = 4; off <= 32; off <<= 1) {
    const ull o = __shfl_xor(t, off, 64);
    if (o > t) t = o;
  }
  int nc = 0;
#pragma unroll
  for (int s = 0; s < 5; ++s) {
    const bool keep = (v[s] <= t) && (v[s] != ~0ull);
    const ull mask = __ballot(keep);
    if (mask) {
      const unsigned pre = mbcnt64(mask);
      if (keep) B[nc + pre] = v[s];
      nc += (int)__popcll(mask);
    }
  }
  tau = t;
  return nc;
}

__global__ __launch_bounds__(256) void knn_wave_kernel(
    const float* __restrict__ locs4s, const int* __restrict__ oidx,
    const int* __restrict__ cellstart, int* __restrict__ knn, int n)
{
#pragma clang fp contract(off)
  constexpr int CAP = 320, TRIG = 256;
  __shared__ ull Bs[4][CAP];
  const int wave = threadIdx.x >> 6, lane = threadIdx.x & 63;
  const int t = blockIdx.x * 4 + wave;   // sorted position of target
  if (t >= n) return;
  ull* B = Bs[wave];

  const float4 L = *(const float4*)(locs4s + (size_t)t*4);
  const float tx = L.x, ty = L.y, tz = L.z, tw = L.w;
  const int cx = min(KNN_G-1, (int)(tx * (float)KNN_G));
  const int cy = min(KNN_G-1, (int)(ty * (float)KNN_G));
  const int cz = min(KNN_G-1, (int)(tz * (float)KNN_G));
  const int cw = min(KNN_G-1, (int)(tw * (float)KNN_G));

  ull tau = ~0ull;       // valid (>= exact) 16th-best bound, wave-uniform
  ull topsave = ~0ull;
  int cnt = 0;

  auto do_range = [&](int ps, int pe) {
    for (int p0 = ps; p0 < pe; p0 += 64) {
      const int p = p0 + lane;
      ull key = ~0ull;
      if (p < pe && p != t) {
        const float4 q = *(const float4*)(locs4s + (size_t)p*4);
        const int oj = oidx[p];
        const float a0 = q.x - tx, a1 = q.y - ty, a2 = q.z - tz, a3 = q.w - tw;
        const float s0 = a0*a0, s1 = a1*a1, s2 = a2*a2, s3 = a3*a3;
        const float d = ((s0 + s1) + s2) + s3;
        key = ((ull)__float_as_uint(d) << 32) | (unsigned)oj;
      }
      const bool surv = key < tau;
      const ull mask = __ballot(surv);
      if (mask) {
        const unsigned pre = mbcnt64(mask);
        if (surv) B[cnt + pre] = key;
        cnt += (int)__popcll(mask);
        if (cnt > TRIG) cnt = knn_filter(B, cnt, lane, tau);
      }
    }
  };

  // level 0: radius-1 block; lane r<27 prefetches combo r's w-range.
  // Process the CENTER combo first (tightest candidates -> early tau).
  int psv = 0, pev = 0;
  if (lane < 27) {
    const int cr = (lane == 0) ? 13 : (lane <= 13 ? lane - 1 : lane);
    const int ax = cx + (cr / 9) - 1;
    const int ay = cy + ((cr / 3) % 3) - 1;
    const int az = cz + (cr % 3) - 1;
    if (ax >= 0 && ax < KNN_G && ay >= 0 && ay < KNN_G &&
        az >= 0 && az < KNN_G) {
      const int base = ((ax*KNN_G + ay)*KNN_G + az)*KNN_G;
      const int wlo = max(cw-1, 0), whi = min(cw+1, KNN_G-1);
      psv = cellstart[base + wlo];
      pev = cellstart[base + whi + 1];
    }
  }
  for (int r = 0; r < 27; ++r) {
    const int ps = __shfl(psv, r, 64);
    const int pe = __shfl(pev, r, 64);
    if (ps < pe) do_range(ps, pe);
  }

  // shells m = 2..G-1 (rare; exact refine before break check)
  for (int m = 2; m <= KNN_G - 1; ++m) {
    if (cnt > 16) { tau = knn_refine16(B, cnt, lane, topsave); cnt = 16; }
    if (tau != ~0ull) {
      const float taud = __uint_as_float((unsigned)(tau >> 32));
      const float r = (float)(m - 1) * (1.0f / (float)KNN_G);
      if (taud < r * r * 0.99999f) break;
    }
    const int xlo = max(cx-m, 0), xhi = min(cx+m, KNN_G-1);
    for (int ax = xlo; ax <= xhi; ++ax) {
      const bool xe = (ax == cx-m) || (ax == cx+m);
      const int ylo = max(cy-m, 0), yhi = min(cy+m, KNN_G-1);
      for (int ay = ylo; ay <= yhi; ++ay) {
        const bool ye = (ay == cy-m) || (ay == cy+m);
        const int zlo = max(cz-m, 0), zhi = min(cz+m, KNN_G-1);
        for (int az = zlo; az <= zhi; ++az) {
          const bool ze = (az == cz-m) || (az == cz+m);
          const int base = ((ax*KNN_G + ay)*KNN_G + az)*KNN_G;
          if (xe | ye | ze) {
            const int wlo = max(cw-m, 0), whi = min(cw+m, KNN_G-1);
            do_range(cellstart[base+wlo], cellstart[base+whi+1]);
          } else {
            if (cw-m >= 0) {
              const int c = base + cw - m;
              do_range(cellstart[c], cellstart[c+1]);
            }
            if (cw+m <= KNN_G-1) {
              const int c = base + cw + m;
              do_range(cellstart[c], cellstart[c+1]);
            }
          }
        }
      }
    }
  }
  (void)knn_refine16(B, cnt, lane, topsave);   // exact top-16
  const int i = oidx[t];
  if (lane < 16) knn[(size_t)i*16 + lane] = (int)(topsave & 0xFFFFFFFFull);
}

// ---------------------------------------------------------------------------
// Static conv message + segment max. One dst per wave; cs_src prefetched
// 64-wide into a register and broadcast via shfl; ea streamed in CSR order.
// ---------------------------------------------------------------------------
__global__ __launch_bounds__(256) void static_msg_kernel(
    const float* __restrict__ R, const float* __restrict__ eac,
    const float* __restrict__ wm, const float* __restrict__ bm,
    const int* __restrict__ cs_src, const int* __restrict__ rowptr,
    float* __restrict__ agg, int n)
{
  __shared__ float wma[64][17];
  for (int idx = threadIdx.x; idx < 1024; idx += 256) {
    const int r = idx >> 4, cc = idx & 15;
    wma[r][cc] = wm[r*80 + cc];
  }
  __syncthreads();
  const int wave = threadIdx.x >> 6, lane = threadIdx.x & 63;
  const int d = blockIdx.x * 4 + wave;
  if (d >= n) return;
  const int beg = rowptr[d], end = rowptr[d+1];
  const float base = bm[lane] - R[(size_t)d*64 + lane];
  const float* wr = wma[lane];
  float vmax = 0.f;
  for (int p0 = beg; p0 < end; p0 += 64) {
    const int mcnt = min(64, end - p0);
    const int sreg = (p0 + lane < end) ? cs_src[p0 + lane] : 0;
    int q = 0;
    for (; q + 2 <= mcnt; q += 2) {
      const int s0 = __shfl(sreg, q, 64);
      const int s1 = __shfl(sreg, q + 1, 64);
      const float r0 = R[(size_t)s0*64 + lane];
      const float r1 = R[(size_t)s1*64 + lane];
      const float4* E4 = (const float4*)(eac + (size_t)(p0 + q)*16);
      const float4 a0 = E4[0], a1 = E4[1], a2 = E4[2], a3 = E4[3];
      const float4 c0 = E4[4], c1 = E4[5], c2 = E4[6], c3 = E4[7];
      float x = base + r0, y = base + r1;
      x = fmaf(a0.x, wr[0],  x); y = fmaf(c0.x, wr[0],  y);
      x = fmaf(a0.y, wr[1],  x); y = fmaf(c0.y, wr[1],  y);
      x = fmaf(a0.z, wr[2],  x); y = fmaf(c0.z, wr[2],  y);
      x = fmaf(a0.w, wr[3],  x); y = fmaf(c0.w, wr[3],  y);
      x = fmaf(a1.x, wr[4],  x); y = fmaf(c1.x, wr[4],  y);
      x = fmaf(a1.y, wr[5],  x); y = fmaf(c1.y, wr[5],  y);
      x = fmaf(a1.z, wr[6],  x); y = fmaf(c1.z, wr[6],  y);
      x = fmaf(a1.w, wr[7],  x); y = fmaf(c1.w, wr[7],  y);
      x = fmaf(a2.x, wr[8],  x); y = fmaf(c2.x, wr[8],  y);
      x = fmaf(a2.y, wr[9],  x); y = fmaf(c2.y, wr[9],  y);
      x = fmaf(a2.z, wr[10], x); y = fmaf(c2.z, wr[10], y);
      x = fmaf(a2.w, wr[11], x); y = fmaf(c2.w, wr[11], y);
      x = fmaf(a3.x, wr[12], x); y = fmaf(c3.x, wr[12], y);
      x = fmaf(a3.y, wr[13], x); y = fmaf(c3.y, wr[13], y);
      x = fmaf(a3.z, wr[14], x); y = fmaf(c3.z, wr[14], y);
      x = fmaf(a3.w, wr[15], x); y = fmaf(c3.w, wr[15], y);
      vmax = fmaxf(vmax, fmaxf(x, y));
    }
    if (q < mcnt) {
      const int s0 = __shfl(sreg, q, 64);
      float x = base + R[(size_t)s0*64 + lane];
      const float4* E4 = (const float4*)(eac + (size_t)(p0 + q)*16);
      const float4 a0 = E4[0], a1 = E4[1], a2 = E4[2], a3 = E4[3];
      x = fmaf(a0.x, wr[0],  x); x = fmaf(a0.y, wr[1],  x);
      x = fmaf(a0.z, wr[2],  x); x = fmaf(a0.w, wr[3],  x);
      x = fmaf(a1.x, wr[4],  x); x = fmaf(a1.y, wr[5],  x);
      x = fmaf(a1.z, wr[6],  x); x = fmaf(a1.w, wr[7],  x);
      x = fmaf(a2.x, wr[8],  x); x = fmaf(a2.y, wr[9],  x);
      x = fmaf(a2.z, wr[10], x); x = fmaf(a2.w, wr[11], x);
      x = fmaf(a3.x, wr[12], x); x = fmaf(a3.y, wr[13], x);
      x = fmaf(a3.z, wr[14], x); x = fmaf(a3.w, wr[15], x);
      vmax = fmaxf(vmax, x);
    }
  }
  agg[(size_t)d*64 + lane] = vmax;
}

// ---------------------------------------------------------------------------
// Pack dyn-layer weights (both layers in one dispatch):
// Wpq[256][64] = [w1a - w1b ; w1b], bpq = [b1 ; 0].
// ---------------------------------------------------------------------------
__global__ __launch_bounds__(256) void pack2_kernel(
    const float* __restrict__ w1A, const float* __restrict__ b1A,
    float* __restrict__ wpqA, float* __restrict__ bpqA,
    const float* __restrict__ w1B, const float* __restrict__ b1B,
    float* __restrict__ wpqB, float* __restrict__ bpqB)
{
  const int gidx = blockIdx.x * 256 + threadIdx.x;
  const int l = gidx >> 13;              // 8192 weight-elems per layer
  const int idx = gidx & 8191;
  const float* w1 = l ? w1B : w1A;
  const float* b1 = l ? b1B : b1A;
  float* wpq = l ? wpqB : wpqA;
  float* bpq = l ? bpqB : bpqA;
  const int o = idx >> 6, i = idx & 63;
  const float a = w1[o*128 + i], b = w1[o*128 + 64 + i];
  wpq[idx] = a - b;
  wpq[128*64 + idx] = b;
  if (idx < 128) { bpq[idx] = b1[idx]; bpq[128 + idx] = 0.f; }
}

// ---------------------------------------------------------------------------
// Generic fp32 linear (unchanged)
// ---------------------------------------------------------------------------
template<bool RELU, bool ACC>
__global__ __launch_bounds__(256) void linear_kernel(
    const float* __restrict__ A, int lda,
    const float* __restrict__ W, int ldw,
    const float* __restrict__ bias,
    float* __restrict__ C, int ldc, int M, int K)
{
  __shared__ float As[32 * 64];
  __shared__ float Ws[16 * 64 * 4];
  const int m0 = blockIdx.x * 32;
  const int c0 = blockIdx.y * 64;
  const int tid = threadIdx.x;
  const int wave = tid >> 6, lane = tid & 63;
  const int c = c0 + lane;

  float acc[8];
#pragma unroll
  for (int t = 0; t < 8; ++t) acc[t] = 0.f;

  for (int kt = 0; kt < K; kt += 64) {
    {
      int idx = tid;
#pragma unroll
      for (int itr = 0; itr < 2; ++itr, idx += 256) {
        const int row = idx >> 4, col4 = idx & 15;
        const int gr = m0 + row;
        float4 v = make_float4(0.f, 0.f, 0.f, 0.f);
        if (gr < M) v = *(const float4*)(A + (size_t)gr*lda + kt + col4*4);
        *(float4*)(As + row*64 + col4*4) = v;
      }
      idx = tid;
#pragma unroll
      for (int itr = 0; itr < 4; ++itr, idx += 256) {
        const int ch = idx & 63, g = idx >> 6;
        const float4 v = *(const float4*)(W + (size_t)(c0 + ch)*ldw + kt + g*4);
        *(float4*)(Ws + idx*4) = v;
      }
    }
    __syncthreads();
    const float* ar = As + wave*8*64;
    for (int g = 0; g < 16; ++g) {
      const float4 w = *(const float4*)(Ws + (g*64 + lane)*4);
#pragma unroll
      for (int t = 0; t < 8; ++t) {
        const float4 a = *(const float4*)(ar + t*64 + g*4);
        acc[t] = fmaf(w.x, a.x, fmaf(w.y, a.y, fmaf(w.z, a.z, fmaf(w.w, a.w, acc[t]))));
      }
    }
    __syncthreads();
  }

  const float b = bias ? bias[c] : 0.f;
#pragma unroll
  for (int t = 0; t < 8; ++t) {
    const int gr = m0 + wave*8 + t;
    if (gr < M) {
      float v = acc[t] + b;
      if (RELU) v = fmaxf(v, 0.f);
      float* cp = C + (size_t)gr*ldc + c;
      if (ACC) v += *cp;
      *cp = v;
    }
  }
}

// ---------------------------------------------------------------------------
// Dynamic conv via MFMA (bf16), unchanged from round 6.
// ---------------------------------------------------------------------------
#define TPW 4   // targets per wave

__global__ __launch_bounds__(256) void dyn_mfma_kernel(
    const float* __restrict__ PQ,
    const float* __restrict__ W2, const float* __restrict__ b2,
    const int* __restrict__ knn, float* __restrict__ out, int ldo, int n)
{
  __shared__ short w2s[64 * 136];      // bf16 [c][k], pitch 136
  __shared__ short Ts[4][17 * 136];    // per-wave T, pitch 136
  const int tid = threadIdx.x;
  const int wave = tid >> 6, lane = tid & 63;

  for (int idx = tid; idx < 64 * 128; idx += 256) {
    const int c = idx >> 7, k = idx & 127;
    w2s[c*136 + k] = f2bf(W2[c*128 + k]);
  }
  __syncthreads();

  short8v bfr[4][4];
#pragma unroll
  for (int nt = 0; nt < 4; ++nt)
#pragma unroll
    for (int kt = 0; kt < 4; ++kt)
      bfr[nt][kt] = *(const short8v*)&w2s[(nt*16 + (lane&15))*136 +
                                          kt*32 + (lane>>4)*8];
  const float b2v = b2[lane];
  short* T = Ts[wave];

  for (int tg = 0; tg < TPW; ++tg) {
    const int i = (blockIdx.x * 4 + wave) * TPW + tg;
    if (i >= n) break;
    const size_t i16 = (size_t)i * 16;

    for (int s = 0; s < 9; ++s) {
      const int slot = lane + 64*s;
      if (slot < 544) {
        const int row = slot >> 5, k4 = slot & 31;
        const int j = (row < 16) ? knn[i16 + row] : i;
        const float4 p = *(const float4*)(PQ + (size_t)i*256 + k4*4);
        const float4 q = *(const float4*)(PQ + (size_t)j*256 + 128 + k4*4);
        const float t0 = fmaxf(p.x + q.x, 0.f), t1 = fmaxf(p.y + q.y, 0.f);
        const float t2 = fmaxf(p.z + q.z, 0.f), t3 = fmaxf(p.w + q.w, 0.f);
        int2 w;
        w.x = ((int)(unsigned short)f2bf(t1) << 16) | (unsigned short)f2bf(t0);
        w.y = ((int)(unsigned short)f2bf(t3) << 16) | (unsigned short)f2bf(t2);
        *(int2*)&T[row*136 + k4*4] = w;
      }
    }

    f32x4 acc0[4], acc1[4];
#pragma unroll
    for (int nt = 0; nt < 4; ++nt) {
      acc0[nt] = (f32x4)0.f;
      acc1[nt] = (f32x4)0.f;
    }
#pragma unroll
    for (int kt = 0; kt < 4; ++kt) {
      const short8v a1 = *(const short8v*)&T[(lane&15)*136 + kt*32 + (lane>>4)*8];
      const short8v a2 = *(const short8v*)&T[16*136 + kt*32 + (lane>>4)*8];
#pragma unroll
      for (int nt = 0; nt < 4; ++nt) {
        acc0[nt] = __builtin_amdgcn_mfma_f32_16x16x32_bf16(a1, bfr[nt][kt], acc0[nt], 0, 0, 0);
        acc1[nt] = __builtin_amdgcn_mfma_f32_16x16x32_bf16(a2, bfr[nt][kt], acc1[nt], 0, 0, 0);
      }
    }

    float v[4];
#pragma unroll
    for (int nt = 0; nt < 4; ++nt) {
      float m = fmaxf(fmaxf(acc0[nt][0], acc0[nt][1]),
                      fmaxf(acc0[nt][2], acc0[nt][3]));
      m = fmaxf(m, acc1[nt][0]);
      m = fmaxf(m, __shfl_xor(m, 16, 64));
      m = fmaxf(m, __shfl_xor(m, 32, 64));
      v[nt] = m;
    }
    const int g = lane >> 4;
    float r = v[0];
    r = (g == 1) ? v[1] : r;
    r = (g == 2) ? v[2] : r;
    r = (g == 3) ? v[3] : r;
    out[(size_t)i*ldo + lane] = fmaxf(r + b2v, 0.f);
  }
}

// ---------------------------------------------------------------------------
// Host orchestration
// ---------------------------------------------------------------------------
extern "C" void kernel_launch(void* const* d_in, const int* in_sizes, int n_in,
                              void* d_out, int out_size, void* d_ws, size_t ws_size,
                              hipStream_t stream)
{
  const float* x   = (const float*)d_in[0];
  const int*   ei  = (const int*)d_in[1];
  const float* ea  = (const float*)d_in[2];
  const float* loc = (const float*)d_in[3];
  const float* sg_wm[3] = {(const float*)d_in[5],  (const float*)d_in[9],  (const float*)d_in[13]};
  const float* sg_bm[3] = {(const float*)d_in[6],  (const float*)d_in[10], (const float*)d_in[14]};
  const float* sg_wu[3] = {(const float*)d_in[7],  (const float*)d_in[11], (const float*)d_in[15]};
  const float* sg_bu[3] = {(const float*)d_in[8],  (const float*)d_in[12], (const float*)d_in[16]};
  const float* dg_w1[2] = {(const float*)d_in[17], (const float*)d_in[21]};
  const float* dg_b1[2] = {(const float*)d_in[18], (const float*)d_in[22]};
  const float* dg_w2[2] = {(const float*)d_in[19], (const float*)d_in[23]};
  const float* dg_b2[2] = {(const float*)d_in[20], (const float*)d_in[24]};
  const float* f1_w = (const float*)d_in[25];
  const float* f1_b = (const float*)d_in[26];
  const float* f2_w = (const float*)d_in[27];
  const float* f2_b = (const float*)d_in[28];
  float* out = (float*)d_out;

  const int n    = in_sizes[0] / 64;
  const int Etot = in_sizes[1] / 2;
  const int* srcp = ei;
  const int* dstp = ei + Etot;

  char* basep = (char*)d_ws;
  size_t cur = 0;
  auto alloc = [&](size_t bytes) -> void* {
    void* p = basep + cur;
    cur = (cur + bytes + 255) & ~(size_t)255;
    return p;
  };
  float* CAT  = (float*)alloc((size_t)n * 320 * 4);
  float* Rb   = (float*)alloc((size_t)n * 64 * 4);
  float* PQb  = (float*)alloc((size_t)n * 256 * 4);
  float* agg  = (float*)alloc((size_t)n * 64 * 4);
  float* fu1  = (float*)alloc((size_t)n * 64 * 4);
  float* wpq[2];
  float* bpq[2];
  wpq[0] = (float*)alloc(256 * 64 * 4);  bpq[0] = (float*)alloc(256 * 4);
  wpq[1] = (float*)alloc(256 * 64 * 4);  bpq[1] = (float*)alloc(256 * 4);
  int* knnb   = (int*)alloc((size_t)n * 16 * 4);
  int* zeros     = (int*)alloc((size_t)(2*KNN_NC + 2*n) * 4);
  int* cellcount = zeros;
  int* cellfill  = zeros + KNN_NC;
  int* deg       = zeros + 2*KNN_NC;
  int* dfill     = zeros + 2*KNN_NC + n;
  int* cellstart = (int*)alloc((size_t)(KNN_NC + 1) * 4);
  int* cellidb   = (int*)alloc((size_t)n * 4);
  float* locs4s  = (float*)alloc((size_t)n * 4 * 4);
  int* oidx      = (int*)alloc((size_t)n * 4);
  int* rowptr    = (int*)alloc((size_t)(n + 1) * 4);
  int* cs_src    = (int*)alloc((size_t)Etot * 4);
  int* cs_eid    = (int*)alloc((size_t)Etot * 4);
  float* ea_csr  = (float*)alloc((size_t)Etot * 16 * 4);
  (void)ws_size; (void)n_in; (void)out_size;

  const int nbE = (Etot + 255) / 256;   // covers n too (E >> n)

  hipMemsetAsync(zeros, 0, (size_t)(2*KNN_NC + 2*n) * 4, stream);
  count2_kernel<<<nbE, 256, 0, stream>>>(loc, cellcount, cellidb, n,
                                         dstp, deg, Etot);
  scan2_kernel<<<2, 1024, 0, stream>>>(cellcount, cellstart, KNN_NC,
                                       (KNN_NC + 1023) / 1024,
                                       deg, rowptr, n, (n + 1023) / 1024);
  scatter2_kernel<<<nbE, 256, 0, stream>>>(loc, cellidb, cellstart, cellfill,
                                           locs4s, oidx, n,
                                           srcp, dstp, rowptr, dfill,
                                           cs_src, cs_eid, Etot);
  knn_wave_kernel<<<(n + 3) / 4, 256, 0, stream>>>(locs4s, oidx, cellstart,
                                                   knnb, n);
  ea_perm_kernel<<<(Etot*4 + 255) / 256, 256, 0, stream>>>(ea, cs_eid,
                                                           ea_csr, Etot);
  pack2_kernel<<<64, 256, 0, stream>>>(dg_w1[0], dg_b1[0], wpq[0], bpq[0],
                                       dg_w1[1], dg_b1[1], wpq[1], bpq[1]);

  const int mb = (n + 31) / 32;
  auto lin = [&](const float* A, int lda, const float* W, int ldw, const float* bias,
                 float* C, int ldc, int K, int ncols, bool relu, bool accum) {
    dim3 grid(mb, ncols / 64);
    if (relu)       linear_kernel<true,  false><<<grid, 256, 0, stream>>>(A, lda, W, ldw, bias, C, ldc, n, K);
    else if (accum) linear_kernel<false, true ><<<grid, 256, 0, stream>>>(A, lda, W, ldw, bias, C, ldc, n, K);
    else            linear_kernel<false, false><<<grid, 256, 0, stream>>>(A, lda, W, ldw, bias, C, ldc, n, K);
  };

  // static layers: x -> h1(CAT+0) -> h2(CAT+192) -> h3(CAT+256)
  const float* hin = x; int hlda = 64;
  float* hout[3] = {CAT + 0, CAT + 192, CAT + 256};
  for (int l = 0; l < 3; ++l) {
    lin(hin, hlda, sg_wm[l] + 16, 80, nullptr, Rb, 64, 64, 64, false, false);
    static_msg_kernel<<<(n + 3) / 4, 256, 0, stream>>>(Rb, ea_csr, sg_wm[l],
                                                       sg_bm[l], cs_src,
                                                       rowptr, agg, n);
    lin(agg, 64, sg_wu[l], 64, sg_bu[l], hout[l], 320, 64, 64, true, false);
    hin = hout[l]; hlda = 320;
  }

  // dynamic layers: h1 -> g1(CAT+64); g1 -> g2(CAT+128)
  const float* din[2] = {CAT + 0, CAT + 64};
  float* doutp[2] = {CAT + 64, CAT + 128};
  const int db = (n + 4*TPW - 1) / (4*TPW);
  for (int l = 0; l < 2; ++l) {
    lin(din[l], 320, wpq[l], 64, bpq[l], PQb, 256, 64, 256, false, false);
    dyn_mfma_kernel<<<db, 256, 0, stream>>>(PQb, dg_w2[l], dg_b2[l],
                                            knnb, doutp[l], 320, n);
  }

  // fusion
  lin(CAT, 320, f1_w, 320, f1_b, fu1, 64, 320, 64, true,  false);
  lin(CAT, 320, f2_w + 64, 384, f2_b, out, 64, 320, 64, false, false);
  lin(fu1, 64, f2_w, 384, nullptr, out, 64, 64, 64, false, true);
}